// Round 8
// baseline (458.711 us; speedup 1.0000x reference)
//
#include <hip/hip_runtime.h>
#include <math.h>

typedef unsigned short ushort_t;
typedef __attribute__((ext_vector_type(8))) short bf16x8;
typedef __attribute__((ext_vector_type(4))) float f32x4;

constexpr int kD      = 768;
constexpr int kNH     = 12;
constexpr int kDK     = 64;
constexpr int kFF     = 3072;
constexpr int kL      = 1024;
constexpr int kRows   = 2048;     // B * L
constexpr float kEPS  = 1e-5f;
constexpr int kMLRows = 24 * kL;  // B*H*L q-rows

__device__ __forceinline__ ushort_t f2bf(float f) {
    union { float f; unsigned u; } v; v.f = f;
    unsigned r = (v.u + 0x7fffu + ((v.u >> 16) & 1u)) >> 16;
    return (ushort_t)r;
}
__device__ __forceinline__ float bf2f(ushort_t u) {
    union { unsigned u; float f; } v; v.u = ((unsigned)u) << 16; return v.f;
}

#define GL_LDS(gp, lp) __builtin_amdgcn_global_load_lds( \
    (const __attribute__((address_space(1))) void*)(gp), \
    (__attribute__((address_space(3))) void*)(lp), 16, 0, 0)

// ---------------------------------------------------------------------------
// bf16 MFMA GEMM (m97 structure): 128x128 tile, BK=32, 4 waves.
// ---------------------------------------------------------------------------
template<int RELU, int OUTBF, int ADDBIAS>
__device__ __forceinline__ void gemm_body(const ushort_t* __restrict__ A,
                                          const ushort_t* __restrict__ WT,
                                          const float* __restrict__ bias,
                                          void* __restrict__ Cout,
                                          int N, int K, int row0, int col0,
                                          int kbeg, int kend)
{
    __shared__ ushort_t lds[8192];
    ushort_t* As = lds;
    ushort_t* Bs = lds + 4096;

    const int tid  = threadIdx.x;
    const int lane = tid & 63;
    const int wave = tid >> 6;
    const int wrow = (wave & 1) * 64;
    const int wcol = (wave >> 1) * 64;

    const int srow = wave * 16 + (lane >> 2);
    const int sk   = (lane & 3) * 8;
    const ushort_t* ga0 = A  + (size_t)(row0 + srow)      * K + sk;
    const ushort_t* ga1 = A  + (size_t)(row0 + srow + 64) * K + sk;
    const ushort_t* gb0 = WT + (size_t)(col0 + srow)      * K + sk;
    const ushort_t* gb1 = WT + (size_t)(col0 + srow + 64) * K + sk;
    ushort_t* la0 = As + wave * 512;
    ushort_t* la1 = As + 2048 + wave * 512;
    ushort_t* lb0 = Bs + wave * 512;
    ushort_t* lb1 = Bs + 2048 + wave * 512;

    const int fl = lane & 15, fq = lane >> 4;
    const ushort_t* fa[4];
    const ushort_t* fb[4];
    #pragma unroll
    for (int i = 0; i < 4; ++i) {
        fa[i] = As + (wrow + i * 16 + fl) * 32 + fq * 8;
        fb[i] = Bs + (wcol + i * 16 + fl) * 32 + fq * 8;
    }

    f32x4 acc[4][4] = {};

    for (int k0 = kbeg; k0 < kend; k0 += 32) {
        __syncthreads();
        GL_LDS(ga0 + k0, la0);
        GL_LDS(ga1 + k0, la1);
        GL_LDS(gb0 + k0, lb0);
        GL_LDS(gb1 + k0, lb1);
        __syncthreads();

        bf16x8 av[4], bv[4];
        #pragma unroll
        for (int i = 0; i < 4; ++i) {
            av[i] = *(const bf16x8*)fa[i];
            bv[i] = *(const bf16x8*)fb[i];
        }
        #pragma unroll
        for (int mi = 0; mi < 4; ++mi)
            #pragma unroll
            for (int ni = 0; ni < 4; ++ni)
                acc[mi][ni] = __builtin_amdgcn_mfma_f32_16x16x32_bf16(
                    av[mi], bv[ni], acc[mi][ni], 0, 0, 0);
    }

    #pragma unroll
    for (int mi = 0; mi < 4; ++mi) {
        const int m = wrow + mi * 16 + fq * 4;
        #pragma unroll
        for (int ni = 0; ni < 4; ++ni) {
            const int n = wcol + ni * 16 + fl;
            const float bb = ADDBIAS ? bias[col0 + n] : 0.f;
            #pragma unroll
            for (int r = 0; r < 4; ++r) {
                float v = acc[mi][ni][r] + bb;
                if (RELU) v = fmaxf(v, 0.f);
                const size_t idx = (size_t)(row0 + m + r) * N + col0 + n;
                if (OUTBF) ((ushort_t*)Cout)[idx] = f2bf(v);
                else       ((float*)Cout)[idx]    = v;
            }
        }
    }
}

template<int RELU, int OUTBF>
__global__ __launch_bounds__(256)
void gemm_kernel(const ushort_t* __restrict__ A, const ushort_t* __restrict__ WT,
                 const float* __restrict__ bias, void* __restrict__ Cout,
                 int N, int K)
{
    gemm_body<RELU, OUTBF, 1>(A, WT, bias, Cout, N, K,
                              blockIdx.y * 128, blockIdx.x * 128, 0, K);
}

__global__ __launch_bounds__(256)
void gemm_splitk_kernel(const ushort_t* __restrict__ A, const ushort_t* __restrict__ WT,
                        float* __restrict__ parts, int N, int K, int kslice)
{
    const int z = blockIdx.z;
    float* out = parts + (size_t)z * kRows * N;
    gemm_body<0, 0, 0>(A, WT, nullptr, out, N, K,
                       blockIdx.y * 128, blockIdx.x * 128, z * kslice, (z + 1) * kslice);
}

__global__ __launch_bounds__(256)
void gemm_qkv_kernel(const ushort_t* __restrict__ A,
                     const ushort_t* wq, const ushort_t* wk, const ushort_t* wv,
                     const float* bq, const float* bk, const float* bv,
                     ushort_t* q, ushort_t* k, ushort_t* v)
{
    const ushort_t* WT; const float* bias; ushort_t* out;
    if (blockIdx.z == 0)      { WT = wq; bias = bq; out = q; }
    else if (blockIdx.z == 1) { WT = wk; bias = bk; out = k; }
    else                      { WT = wv; bias = bv; out = v; }
    gemm_body<0, 1, 1>(A, WT, bias, out, kD, kD,
                       blockIdx.y * 128, blockIdx.x * 128, 0, kD);
}

// ---------------------------------------------------------------------------
// Weight transpose + fp32->bf16:  W[K][N] -> WT[N][K] bf16.
// ---------------------------------------------------------------------------
struct WtDesc { const float* src; ushort_t* dst; int K; int N; };
struct WtArgs { WtDesc d[3]; };

__global__ __launch_bounds__(256)
void wt_kernel(WtArgs args)
{
    const WtDesc w = args.d[blockIdx.z];
    const int ktiles = w.K >> 6;
    const int kt = (blockIdx.x % ktiles) * 64;
    const int nt = (blockIdx.x / ktiles) * 64;
    if (nt >= w.N) return;

    __shared__ float T[64][65];
    const int tid = threadIdx.x;
    #pragma unroll
    for (int i = 0; i < 4; ++i) {
        const int e = tid + i * 256;
        const int r = e >> 4;
        const int c = (e & 15) * 4;
        const float4 f = *(const float4*)&w.src[(size_t)(kt + r) * w.N + nt + c];
        T[c + 0][r] = f.x; T[c + 1][r] = f.y; T[c + 2][r] = f.z; T[c + 3][r] = f.w;
    }
    __syncthreads();
    #pragma unroll
    for (int i = 0; i < 4; ++i) {
        const int e = tid + i * 256;
        const int n = e >> 4;
        const int kc = (e & 15) * 4;
        ushort4 o;
        o.x = f2bf(T[n][kc + 0]); o.y = f2bf(T[n][kc + 1]);
        o.z = f2bf(T[n][kc + 2]); o.w = f2bf(T[n][kc + 3]);
        *(ushort4*)&w.dst[(size_t)(nt + n) * w.K + kt + kc] = o;
    }
}

// fp32 -> bf16 elementwise
__global__ __launch_bounds__(256)
void cvt_kernel(const float* __restrict__ in, ushort_t* __restrict__ out, int n4)
{
    const int i = blockIdx.x * 256 + threadIdx.x;
    if (i < n4) {
        const float4 f = ((const float4*)in)[i];
        ushort4 o;
        o.x = f2bf(f.x); o.y = f2bf(f.y); o.z = f2bf(f.z); o.w = f2bf(f.w);
        ((ushort4*)out)[i] = o;
    }
}

// ---------------------------------------------------------------------------
// V transpose per head: vb[b*L+j][h*64+d] -> vt[(b*12+h)*64+d][j]
// ---------------------------------------------------------------------------
__global__ __launch_bounds__(256)
void vtrans_kernel(const ushort_t* __restrict__ vb, ushort_t* __restrict__ vt)
{
    const int bh = blockIdx.x;
    const int b = bh / kNH, h = bh - b * kNH;
    const int j0 = blockIdx.y * 64;
    __shared__ ushort_t T[64][72];

    const int tid = threadIdx.x;
    {
        const int jr = tid & 63;
        const int c0 = (tid >> 6) * 16;
        const ushort_t* sp = vb + (size_t)(b * kL + j0 + jr) * kD + h * kDK + c0;
        uint4 u0 = *(const uint4*)sp;
        uint4 u1 = *(const uint4*)(sp + 8);
        const ushort_t* e0 = (const ushort_t*)&u0;
        const ushort_t* e1 = (const ushort_t*)&u1;
        #pragma unroll
        for (int jj = 0; jj < 8; ++jj) {
            T[c0 + jj][jr]     = e0[jj];
            T[c0 + 8 + jj][jr] = e1[jj];
        }
    }
    __syncthreads();
    {
        const int dr = tid >> 2;
        const int jc = (tid & 3) * 16;
        ushort_t* dp = vt + (size_t)(bh * 64 + dr) * kL + j0 + jc;
        *(uint4*)dp       = *(const uint4*)&T[dr][jc];
        *(uint4*)(dp + 8) = *(const uint4*)&T[dr][jc + 8];
    }
}

// ---------------------------------------------------------------------------
// Relative-position bias table in MFMA-fragment order (see R5/R6 notes).
// ---------------------------------------------------------------------------
__global__ __launch_bounds__(256, 4)
void bias_kernel(const float* __restrict__ sx, const float* __restrict__ sy,
                 const float* __restrict__ P1, const float* __restrict__ pb1,
                 const float* __restrict__ P2, const float* __restrict__ pb2,
                 ushort_t* __restrict__ biasb)
{
    const int bid = blockIdx.x;
    const int b  = bid >> 10;
    const int qt = (bid >> 4) & 63;
    const int kt = bid & 15;
    const int tid = threadIdx.x;

    __shared__ float P[32][16];       // [u] = {A,B,C,0, W2[0..11]}
    __shared__ float pb2l[12];
    __shared__ float qxl[16], qyl[16], kxl[64], kyl[64];
    __shared__ ushort_t Btile[12 * 1024];   // 24 KB

    if (tid < 32) {
        P[tid][0] = P1[tid];
        P[tid][1] = P1[32 + tid];
        P[tid][2] = pb1[tid];
        P[tid][3] = 0.f;
    }
    for (int e = tid; e < 384; e += 256) P[e / 12][4 + e % 12] = P2[e];
    if (tid < 12) pb2l[tid] = pb2[tid];
    if (tid < 16) { qxl[tid] = sx[b * kL + qt * 16 + tid];
                    qyl[tid] = sy[b * kL + qt * 16 + tid]; }
    if (tid < 64) { kxl[tid] = sx[b * kL + kt * 64 + tid];
                    kyl[tid] = sy[b * kL + kt * 64 + tid]; }
    __syncthreads();

    const int ri = tid >> 4;
    const int fl = tid & 15;
    const int fq = ri >> 2, r = ri & 3;
    const int lane16 = fq * 16 + fl;
    const float xi = qxl[ri], yi = qyl[ri];

    float rx[4], ry[4];
    #pragma unroll
    for (int n = 0; n < 4; ++n) {
        const int cj = n * 16 + fl;
        rx[n] = fminf(fmaxf(xi - kxl[cj], -1000.f), 1000.f) * 1e-3f;
        ry[n] = fminf(fmaxf(yi - kyl[cj], -1000.f), 1000.f) * 1e-3f;
    }

    float acc[4][12] = {};
    #pragma unroll 4
    for (int u = 0; u < 32; ++u) {
        const float4 pc = *(const float4*)&P[u][0];
        const float4 w0 = *(const float4*)&P[u][4];
        const float4 w1 = *(const float4*)&P[u][8];
        const float4 w2 = *(const float4*)&P[u][12];
        float t[4];
        #pragma unroll
        for (int n = 0; n < 4; ++n)
            t[n] = fmaxf(fmaf(rx[n], pc.x, fmaf(ry[n], pc.y, pc.z)), 0.f);
        #pragma unroll
        for (int n = 0; n < 4; ++n) {
            acc[n][0]  = fmaf(t[n], w0.x, acc[n][0]);
            acc[n][1]  = fmaf(t[n], w0.y, acc[n][1]);
            acc[n][2]  = fmaf(t[n], w0.z, acc[n][2]);
            acc[n][3]  = fmaf(t[n], w0.w, acc[n][3]);
            acc[n][4]  = fmaf(t[n], w1.x, acc[n][4]);
            acc[n][5]  = fmaf(t[n], w1.y, acc[n][5]);
            acc[n][6]  = fmaf(t[n], w1.z, acc[n][6]);
            acc[n][7]  = fmaf(t[n], w1.w, acc[n][7]);
            acc[n][8]  = fmaf(t[n], w2.x, acc[n][8]);
            acc[n][9]  = fmaf(t[n], w2.y, acc[n][9]);
            acc[n][10] = fmaf(t[n], w2.z, acc[n][10]);
            acc[n][11] = fmaf(t[n], w2.w, acc[n][11]);
        }
    }

    #pragma unroll
    for (int h = 0; h < 12; ++h) {
        const float pb = pb2l[h];
        #pragma unroll
        for (int n = 0; n < 4; ++n)
            Btile[h * 1024 + lane16 * 16 + n * 4 + r] = f2bf(acc[n][h] + pb);
    }
    __syncthreads();

    #pragma unroll
    for (int i = 0; i < 6; ++i) {
        const int off = (i * 256 + tid) * 8;
        const int h = off >> 10;
        const int inner = off & 1023;
        ushort_t* dst = biasb +
            (((size_t)(b * kNH + h) * 64 + qt) * 16 + kt) * 1024 + inner;
        *(uint4*)dst = *(const uint4*)&Btile[off];
    }
}

// ---------------------------------------------------------------------------
// MFMA flash attention, split-K z=0..3 (256 keys / 4 tiles each).
// Online softmax (m,l) — the R6-proven body.  6144 one-wave blocks ->
// 6 waves/SIMD with __launch_bounds__(64,6) (R6 VGPR_Count=80 <= 85 cap).
// Partials: normalized bf16 O per split + per-row (m,l) fp32.
// ---------------------------------------------------------------------------
__global__ __launch_bounds__(64, 6)
void attn_kernel(const ushort_t* __restrict__ qg, const ushort_t* __restrict__ kg,
                 const ushort_t* __restrict__ vt, const ushort_t* __restrict__ biasb,
                 ushort_t* __restrict__ p0, ushort_t* __restrict__ p1,
                 ushort_t* __restrict__ p2, ushort_t* __restrict__ p3,
                 float2* __restrict__ ml)
{
    const int bh = blockIdx.x;
    const int b  = bh / kNH, h = bh - b * kNH;
    const int qt = blockIdx.y;
    const int q0 = qt * 16;
    const int z  = blockIdx.z;
    const int lane = threadIdx.x;
    const int fl = lane & 15, fq = lane >> 4;

    __shared__ ushort_t Sp[16][72];

    const size_t qoff = (size_t)(b * kL + q0 + fl) * kD + h * kDK + fq * 8;
    const bf16x8 aq0 = *(const bf16x8*)(qg + qoff);
    const bf16x8 aq1 = *(const bf16x8*)(qg + qoff + 32);

    const ushort_t* kbase = kg + (size_t)(b * kL) * kD + h * kDK + fq * 8;
    const ushort_t* vbase = vt + (size_t)(bh * 64) * kL + fq * 8;
    const ushort_t* btile = biasb +
        ((size_t)(bh * 64 + qt) * 16 + z * 4) * 1024 + lane * 16;

    f32x4 accO[4] = {};
    float m_run[4] = {-INFINITY, -INFINITY, -INFINITY, -INFINITY};
    float l_run[4] = {};

    bf16x8 kc[4][2];
    uint4 bc0, bc1;
    {
        const int k0 = z * 256;
        #pragma unroll
        for (int n = 0; n < 4; ++n) {
            const ushort_t* kr = kbase + (size_t)(k0 + n * 16 + fl) * kD;
            kc[n][0] = *(const bf16x8*)kr;
            kc[n][1] = *(const bf16x8*)(kr + 32);
        }
        bc0 = *(const uint4*)btile;
        bc1 = *(const uint4*)(btile + 8);
    }

    #pragma unroll
    for (int t = 0; t < 4; ++t) {
        const int k0 = z * 256 + t * 64;

        bf16x8 vv[4][2];
        #pragma unroll
        for (int n = 0; n < 4; ++n) {
            const ushort_t* vr = vbase + (size_t)(n * 16 + fl) * kL + k0;
            vv[n][0] = *(const bf16x8*)vr;
            vv[n][1] = *(const bf16x8*)(vr + 32);
        }

        f32x4 S[4] = {};
        #pragma unroll
        for (int n = 0; n < 4; ++n) {
            S[n] = __builtin_amdgcn_mfma_f32_16x16x32_bf16(aq0, kc[n][0], S[n], 0, 0, 0);
            S[n] = __builtin_amdgcn_mfma_f32_16x16x32_bf16(aq1, kc[n][1], S[n], 0, 0, 0);
        }

        bf16x8 kn[4][2];
        uint4 bn0, bn1;
        if (t < 3) {
            #pragma unroll
            for (int n = 0; n < 4; ++n) {
                const ushort_t* kr = kbase + (size_t)(k0 + 64 + n * 16 + fl) * kD;
                kn[n][0] = *(const bf16x8*)kr;
                kn[n][1] = *(const bf16x8*)(kr + 32);
            }
            bn0 = *(const uint4*)(btile + (t + 1) * 1024);
            bn1 = *(const uint4*)(btile + (t + 1) * 1024 + 8);
        }

        ushort_t bu[16];
        *(uint4*)&bu[0] = bc0;
        *(uint4*)&bu[8] = bc1;
        #pragma unroll
        for (int n = 0; n < 4; ++n)
            #pragma unroll
            for (int r = 0; r < 4; ++r)
                S[n][r] = fmaf(S[n][r], 0.125f, bf2f(bu[n * 4 + r]));

        #pragma unroll
        for (int r = 0; r < 4; ++r) {
            float mx = fmaxf(fmaxf(S[0][r], S[1][r]), fmaxf(S[2][r], S[3][r]));
            mx = fmaxf(mx, __shfl_xor(mx, 1, 16));
            mx = fmaxf(mx, __shfl_xor(mx, 2, 16));
            mx = fmaxf(mx, __shfl_xor(mx, 4, 16));
            mx = fmaxf(mx, __shfl_xor(mx, 8, 16));
            const float mnew  = fmaxf(m_run[r], mx);
            const float alpha = __expf(m_run[r] - mnew);
            float ls = 0.f;
            #pragma unroll
            for (int n = 0; n < 4; ++n) {
                const float e = __expf(S[n][r] - mnew);
                S[n][r] = e;
                ls += e;
            }
            ls += __shfl_xor(ls, 1, 16);
            ls += __shfl_xor(ls, 2, 16);
            ls += __shfl_xor(ls, 4, 16);
            ls += __shfl_xor(ls, 8, 16);
            l_run[r] = l_run[r] * alpha + ls;
            m_run[r] = mnew;
            #pragma unroll
            for (int n = 0; n < 4; ++n) accO[n][r] *= alpha;
        }

        #pragma unroll
        for (int n = 0; n < 4; ++n)
            #pragma unroll
            for (int r = 0; r < 4; ++r)
                Sp[fq * 4 + r][n * 16 + fl] = f2bf(S[n][r]);
        __syncthreads();

        const bf16x8 ap0 = *(const bf16x8*)&Sp[fl][fq * 8];
        const bf16x8 ap1 = *(const bf16x8*)&Sp[fl][32 + fq * 8];
        #pragma unroll
        for (int n = 0; n < 4; ++n) {
            accO[n] = __builtin_amdgcn_mfma_f32_16x16x32_bf16(ap0, vv[n][0], accO[n], 0, 0, 0);
            accO[n] = __builtin_amdgcn_mfma_f32_16x16x32_bf16(ap1, vv[n][1], accO[n], 0, 0, 0);
        }
        __syncthreads();

        if (t < 3) {
            #pragma unroll
            for (int n = 0; n < 4; ++n) { kc[n][0] = kn[n][0]; kc[n][1] = kn[n][1]; }
            bc0 = bn0; bc1 = bn1;
        }
    }

    ushort_t* p = (z == 0) ? p0 : (z == 1) ? p1 : (z == 2) ? p2 : p3;
    float inv[4];
    #pragma unroll
    for (int r = 0; r < 4; ++r) inv[r] = 1.0f / l_run[r];
    #pragma unroll
    for (int n = 0; n < 4; ++n)
        #pragma unroll
        for (int r = 0; r < 4; ++r)
            p[(size_t)(b * kL + q0 + fq * 4 + r) * kD + h * kDK + n * 16 + fl] =
                f2bf(accO[n][r] * inv[r]);
    if (fl == 0) {
        #pragma unroll
        for (int r = 0; r < 4; ++r)
            ml[(size_t)z * kMLRows + bh * kL + q0 + fq * 4 + r] =
                make_float2(m_run[r], l_run[r]);
    }
}

// ---------------------------------------------------------------------------
// Combine the four attention splits: w_z ∝ e^{m_z - M} l_z.
// ---------------------------------------------------------------------------
__global__ __launch_bounds__(256)
void attn_combine_kernel(const ushort_t* __restrict__ p0, const ushort_t* __restrict__ p1,
                         const ushort_t* __restrict__ p2, const ushort_t* __restrict__ p3,
                         const float2* __restrict__ ml, ushort_t* __restrict__ out)
{
    const int tid = threadIdx.x;
    const int R = blockIdx.x * 32 + (tid >> 3);
    const int bh = R >> 10, i = R & 1023;
    const int b = bh / kNH, h = bh - b * kNH;

    const float2 s0 = ml[bh * kL + i];
    const float2 s1 = ml[kMLRows + bh * kL + i];
    const float2 s2 = ml[2 * kMLRows + bh * kL + i];
    const float2 s3 = ml[3 * kMLRows + bh * kL + i];
    const float M  = fmaxf(fmaxf(s0.x, s1.x), fmaxf(s2.x, s3.x));
    const float w0 = __expf(s0.x - M) * s0.y;
    const float w1 = __expf(s1.x - M) * s1.y;
    const float w2 = __expf(s2.x - M) * s2.y;
    const float w3 = __expf(s3.x - M) * s3.y;
    const float inv = 1.0f / (w0 + w1 + w2 + w3);
    const float c0 = w0 * inv, c1 = w1 * inv, c2 = w2 * inv, c3 = w3 * inv;

    const size_t base = (size_t)(b * kL + i) * kD + h * kDK + (tid & 7) * 8;
    uint4 u0 = *(const uint4*)(p0 + base);
    uint4 u1 = *(const uint4*)(p1 + base);
    uint4 u2 = *(const uint4*)(p2 + base);
    uint4 u3 = *(const uint4*)(p3 + base);
    const ushort_t* e0 = (const ushort_t*)&u0;
    const ushort_t* e1 = (const ushort_t*)&u1;
    const ushort_t* e2 = (const ushort_t*)&u2;
    const ushort_t* e3 = (const ushort_t*)&u3;
    ushort_t o[8];
    #pragma unroll
    for (int j = 0; j < 8; ++j)
        o[j] = f2bf(fmaf(c0, bf2f(e0[j]), fmaf(c1, bf2f(e1[j]),
                    fmaf(c2, bf2f(e2[j]), c3 * bf2f(e3[j])))));
    *(uint4*)(out + base) = *(const uint4*)o;
}

// ---------------------------------------------------------------------------
// Residual + split-K reduce + bias + LayerNorm.
// ---------------------------------------------------------------------------
template<int NPART, int DUAL>
__global__ __launch_bounds__(256)
void ln_kernel(const float* __restrict__ a, const float* __restrict__ parts,
               const float* __restrict__ bias,
               const float* __restrict__ g, const float* __restrict__ be,
               float* __restrict__ out, ushort_t* __restrict__ out_bf)
{
    const int row = blockIdx.x;
    const int tid = threadIdx.x;
    const float* pa = a + (size_t)row * kD;
    constexpr size_t NTOK = (size_t)kRows * kD;

    float v[3];
    float s = 0.f, sq = 0.f;
    #pragma unroll
    for (int i = 0; i < 3; ++i) {
        const int d = tid + i * 256;
        float t = pa[d] + bias[d];
        #pragma unroll
        for (int p = 0; p < NPART; ++p)
            t += parts[p * NTOK + (size_t)row * kD + d];
        v[i] = t;
        s  += t;
        sq += t * t;
    }
    #pragma unroll
    for (int off = 32; off > 0; off >>= 1) {
        s  += __shfl_down(s, off);
        sq += __shfl_down(sq, off);
    }
    __shared__ float bs[4], bq2[4];
    if ((tid & 63) == 0) { bs[tid >> 6] = s; bq2[tid >> 6] = sq; }
    __syncthreads();
    const float ts = bs[0] + bs[1] + bs[2] + bs[3];
    const float tq = bq2[0] + bq2[1] + bq2[2] + bq2[3];
    const float invn = 1.0f / (float)kD;
    const float mean = ts * invn;
    const float var  = tq * invn - mean * mean;
    const float rstd = rsqrtf(var + kEPS);

    float* po = out + (size_t)row * kD;
    #pragma unroll
    for (int i = 0; i < 3; ++i) {
        const int d = tid + i * 256;
        const float o = (v[i] - mean) * rstd * g[d] + be[d];
        po[d] = o;
        if (DUAL) out_bf[(size_t)row * kD + d] = f2bf(o);
    }
}

// ---------------------------------------------------------------------------
extern "C" void kernel_launch(void* const* d_in, const int* in_sizes, int n_in,
                              void* d_out, int out_size, void* d_ws, size_t ws_size,
                              hipStream_t stream)
{
    const float* src = (const float*)d_in[0];
    const float* sx  = (const float*)d_in[1];
    const float* sy  = (const float*)d_in[2];
    const float* Wq  = (const float*)d_in[3];  const float* bq  = (const float*)d_in[4];
    const float* Wk  = (const float*)d_in[5];  const float* bk  = (const float*)d_in[6];
    const float* Wv  = (const float*)d_in[7];  const float* bv  = (const float*)d_in[8];
    const float* Wo  = (const float*)d_in[9];  const float* bo  = (const float*)d_in[10];
    const float* P1  = (const float*)d_in[11]; const float* pb1 = (const float*)d_in[12];
    const float* P2  = (const float*)d_in[13]; const float* pb2 = (const float*)d_in[14];
    const float* W1  = (const float*)d_in[15]; const float* b1  = (const float*)d_in[16];
    const float* W2  = (const float*)d_in[17]; const float* b2  = (const float*)d_in[18];
    const float* g1  = (const float*)d_in[19]; const float* be1 = (const float*)d_in[20];
    const float* g2  = (const float*)d_in[21]; const float* be2 = (const float*)d_in[22];

    // ---- workspace arena (ushort units) ----
    constexpr size_t W768  = 768u * 768u;
    constexpr size_t W3072 = 768u * 3072u;
    constexpr size_t NTOK  = (size_t)kRows * kD;

    ushort_t* wsu = (ushort_t*)d_ws;
    ushort_t* wqT = wsu;                 // dead after QKV -> reused as ml buffer
    ushort_t* wkT = wqT + W768;
    ushort_t* wvT = wkT + W768;
    ushort_t* qb  = wvT + W768;          // Q -> (after combine) attn out -> xbf
    ushort_t* kb  = qb + NTOK;
    ushort_t* vb  = kb + NTOK;           // V -> attn partial O (split 1)
    ushort_t* sb  = vb + NTOK;           // src_bf -> attn partial O (split 0)
    ushort_t* vtb = sb + NTOK;
    ushort_t* biasb = vtb + NTOK;        // 50 MB bias; reused after attn:
    ushort_t* woT   = biasb;
    ushort_t* w1T   = woT + W768;
    ushort_t* w2T   = w1T + W3072;
    float*    xb    = (float*)(w2T + W3072);
    ushort_t* h1bf  = (ushort_t*)(xb + NTOK);
    float*    s2p   = (float*)h1bf;
    float*    ff2p  = (float*)(h1bf + 4 * NTOK);
    float2*   mlb   = (float2*)wqT;      // 786 KB (4 splits), alias of dead wqT
    ushort_t* p2b   = (ushort_t*)d_out;  // d_out (6.29 MB) = p2 + p3 scratch
    ushort_t* p3b   = p2b + NTOK;        //   (consumed by combine, before LN2 writes)
    ushort_t* xbf   = qb;

    const dim3 blk(256);

    WtArgs wa_early;
    wa_early.d[0] = { Wq, wqT, kD, kD };
    wa_early.d[1] = { Wk, wkT, kD, kD };
    wa_early.d[2] = { Wv, wvT, kD, kD };
    wt_kernel<<<dim3(144, 1, 3), blk, 0, stream>>>(wa_early);
    cvt_kernel<<<dim3((int)(NTOK / 4 / 256)), blk, 0, stream>>>(src, sb, (int)(NTOK / 4));
    bias_kernel<<<dim3(2048), blk, 0, stream>>>(sx, sy, P1, pb1, P2, pb2, biasb);

    gemm_qkv_kernel<<<dim3(kD / 128, kRows / 128, 3), blk, 0, stream>>>(
        sb, wqT, wkT, wvT, bq, bk, bv, qb, kb, vb);

    vtrans_kernel<<<dim3(2 * kNH, kL / 64), blk, 0, stream>>>(vb, vtb);

    // attention: split-K=4 (p0=sb, p1=vb, p2/p3=d_out scratch; ml in dead wqT)
    attn_kernel<<<dim3(2 * kNH, kL / 16, 4), dim3(64), 0, stream>>>(
        qb, kb, vtb, biasb, sb, vb, p2b, p3b, mlb);
    attn_combine_kernel<<<dim3(768), blk, 0, stream>>>(sb, vb, p2b, p3b, mlb, qb);

    WtArgs wa_late;
    wa_late.d[0] = { Wo, woT, kD,  kD  };
    wa_late.d[1] = { W1, w1T, kD,  kFF };
    wa_late.d[2] = { W2, w2T, kFF, kD  };
    wt_kernel<<<dim3(576, 1, 3), blk, 0, stream>>>(wa_late);

    gemm_splitk_kernel<<<dim3(kD / 128, kRows / 128, 2), blk, 0, stream>>>(
        qb, woT, s2p, kD, kD, kD / 2);

    ln_kernel<2, 1><<<dim3(kRows), blk, 0, stream>>>(src, s2p, bo, g1, be1, xb, xbf);

    gemm_kernel<1, 1><<<dim3(kFF / 128, kRows / 128), blk, 0, stream>>>(
        xbf, w1T, b1, h1bf, kFF, kD);

    gemm_splitk_kernel<<<dim3(kD / 128, kRows / 128, 3), blk, 0, stream>>>(
        h1bf, w2T, ff2p, kD, kFF, kFF / 3);

    ln_kernel<3, 0><<<dim3(kRows), blk, 0, stream>>>(xb, ff2p, b2, g2, be2,
                                                     (float*)d_out, nullptr);
}

// Round 9
// 334.562 us; speedup vs baseline: 1.3711x; 1.3711x over previous
//
#include <hip/hip_runtime.h>
#include <math.h>

typedef unsigned short ushort_t;
typedef __attribute__((ext_vector_type(8))) short bf16x8;
typedef __attribute__((ext_vector_type(4))) float f32x4;

constexpr int kD      = 768;
constexpr int kNH     = 12;
constexpr int kDK     = 64;
constexpr int kFF     = 3072;
constexpr int kL      = 1024;
constexpr int kRows   = 2048;     // B * L
constexpr float kEPS  = 1e-5f;
constexpr int kMLRows = 24 * kL;  // B*H*L q-rows

__device__ __forceinline__ ushort_t f2bf(float f) {
    union { float f; unsigned u; } v; v.f = f;
    unsigned r = (v.u + 0x7fffu + ((v.u >> 16) & 1u)) >> 16;
    return (ushort_t)r;
}
__device__ __forceinline__ float bf2f(ushort_t u) {
    union { unsigned u; float f; } v; v.u = ((unsigned)u) << 16; return v.f;
}

#define GL_LDS(gp, lp) __builtin_amdgcn_global_load_lds( \
    (const __attribute__((address_space(1))) void*)(gp), \
    (__attribute__((address_space(3))) void*)(lp), 16, 0, 0)

// ---------------------------------------------------------------------------
// bf16 MFMA GEMM (m97 structure): 128x128 tile, BK=32, 4 waves.
// ---------------------------------------------------------------------------
template<int RELU, int OUTBF, int ADDBIAS>
__device__ __forceinline__ void gemm_body(const ushort_t* __restrict__ A,
                                          const ushort_t* __restrict__ WT,
                                          const float* __restrict__ bias,
                                          void* __restrict__ Cout,
                                          int N, int K, int row0, int col0,
                                          int kbeg, int kend)
{
    __shared__ ushort_t lds[8192];
    ushort_t* As = lds;
    ushort_t* Bs = lds + 4096;

    const int tid  = threadIdx.x;
    const int lane = tid & 63;
    const int wave = tid >> 6;
    const int wrow = (wave & 1) * 64;
    const int wcol = (wave >> 1) * 64;

    const int srow = wave * 16 + (lane >> 2);
    const int sk   = (lane & 3) * 8;
    const ushort_t* ga0 = A  + (size_t)(row0 + srow)      * K + sk;
    const ushort_t* ga1 = A  + (size_t)(row0 + srow + 64) * K + sk;
    const ushort_t* gb0 = WT + (size_t)(col0 + srow)      * K + sk;
    const ushort_t* gb1 = WT + (size_t)(col0 + srow + 64) * K + sk;
    ushort_t* la0 = As + wave * 512;
    ushort_t* la1 = As + 2048 + wave * 512;
    ushort_t* lb0 = Bs + wave * 512;
    ushort_t* lb1 = Bs + 2048 + wave * 512;

    const int fl = lane & 15, fq = lane >> 4;
    const ushort_t* fa[4];
    const ushort_t* fb[4];
    #pragma unroll
    for (int i = 0; i < 4; ++i) {
        fa[i] = As + (wrow + i * 16 + fl) * 32 + fq * 8;
        fb[i] = Bs + (wcol + i * 16 + fl) * 32 + fq * 8;
    }

    f32x4 acc[4][4] = {};

    for (int k0 = kbeg; k0 < kend; k0 += 32) {
        __syncthreads();
        GL_LDS(ga0 + k0, la0);
        GL_LDS(ga1 + k0, la1);
        GL_LDS(gb0 + k0, lb0);
        GL_LDS(gb1 + k0, lb1);
        __syncthreads();

        bf16x8 av[4], bv[4];
        #pragma unroll
        for (int i = 0; i < 4; ++i) {
            av[i] = *(const bf16x8*)fa[i];
            bv[i] = *(const bf16x8*)fb[i];
        }
        #pragma unroll
        for (int mi = 0; mi < 4; ++mi)
            #pragma unroll
            for (int ni = 0; ni < 4; ++ni)
                acc[mi][ni] = __builtin_amdgcn_mfma_f32_16x16x32_bf16(
                    av[mi], bv[ni], acc[mi][ni], 0, 0, 0);
    }

    #pragma unroll
    for (int mi = 0; mi < 4; ++mi) {
        const int m = wrow + mi * 16 + fq * 4;
        #pragma unroll
        for (int ni = 0; ni < 4; ++ni) {
            const int n = wcol + ni * 16 + fl;
            const float bb = ADDBIAS ? bias[col0 + n] : 0.f;
            #pragma unroll
            for (int r = 0; r < 4; ++r) {
                float v = acc[mi][ni][r] + bb;
                if (RELU) v = fmaxf(v, 0.f);
                const size_t idx = (size_t)(row0 + m + r) * N + col0 + n;
                if (OUTBF) ((ushort_t*)Cout)[idx] = f2bf(v);
                else       ((float*)Cout)[idx]    = v;
            }
        }
    }
}

template<int RELU, int OUTBF>
__global__ __launch_bounds__(256)
void gemm_kernel(const ushort_t* __restrict__ A, const ushort_t* __restrict__ WT,
                 const float* __restrict__ bias, void* __restrict__ Cout,
                 int N, int K)
{
    gemm_body<RELU, OUTBF, 1>(A, WT, bias, Cout, N, K,
                              blockIdx.y * 128, blockIdx.x * 128, 0, K);
}

__global__ __launch_bounds__(256)
void gemm_splitk_kernel(const ushort_t* __restrict__ A, const ushort_t* __restrict__ WT,
                        float* __restrict__ parts, int N, int K, int kslice)
{
    const int z = blockIdx.z;
    float* out = parts + (size_t)z * kRows * N;
    gemm_body<0, 0, 0>(A, WT, nullptr, out, N, K,
                       blockIdx.y * 128, blockIdx.x * 128, z * kslice, (z + 1) * kslice);
}

__global__ __launch_bounds__(256)
void gemm_qkv_kernel(const ushort_t* __restrict__ A,
                     const ushort_t* wq, const ushort_t* wk, const ushort_t* wv,
                     const float* bq, const float* bk, const float* bv,
                     ushort_t* q, ushort_t* k, ushort_t* v)
{
    const ushort_t* WT; const float* bias; ushort_t* out;
    if (blockIdx.z == 0)      { WT = wq; bias = bq; out = q; }
    else if (blockIdx.z == 1) { WT = wk; bias = bk; out = k; }
    else                      { WT = wv; bias = bv; out = v; }
    gemm_body<0, 1, 1>(A, WT, bias, out, kD, kD,
                       blockIdx.y * 128, blockIdx.x * 128, 0, kD);
}

// ---------------------------------------------------------------------------
// Weight transpose + fp32->bf16:  W[K][N] -> WT[N][K] bf16.
// ---------------------------------------------------------------------------
struct WtDesc { const float* src; ushort_t* dst; int K; int N; };
struct WtArgs { WtDesc d[3]; };

__global__ __launch_bounds__(256)
void wt_kernel(WtArgs args)
{
    const WtDesc w = args.d[blockIdx.z];
    const int ktiles = w.K >> 6;
    const int kt = (blockIdx.x % ktiles) * 64;
    const int nt = (blockIdx.x / ktiles) * 64;
    if (nt >= w.N) return;

    __shared__ float T[64][65];
    const int tid = threadIdx.x;
    #pragma unroll
    for (int i = 0; i < 4; ++i) {
        const int e = tid + i * 256;
        const int r = e >> 4;
        const int c = (e & 15) * 4;
        const float4 f = *(const float4*)&w.src[(size_t)(kt + r) * w.N + nt + c];
        T[c + 0][r] = f.x; T[c + 1][r] = f.y; T[c + 2][r] = f.z; T[c + 3][r] = f.w;
    }
    __syncthreads();
    #pragma unroll
    for (int i = 0; i < 4; ++i) {
        const int e = tid + i * 256;
        const int n = e >> 4;
        const int kc = (e & 15) * 4;
        ushort4 o;
        o.x = f2bf(T[n][kc + 0]); o.y = f2bf(T[n][kc + 1]);
        o.z = f2bf(T[n][kc + 2]); o.w = f2bf(T[n][kc + 3]);
        *(ushort4*)&w.dst[(size_t)(nt + n) * w.K + kt + kc] = o;
    }
}

// fp32 -> bf16 elementwise
__global__ __launch_bounds__(256)
void cvt_kernel(const float* __restrict__ in, ushort_t* __restrict__ out, int n4)
{
    const int i = blockIdx.x * 256 + threadIdx.x;
    if (i < n4) {
        const float4 f = ((const float4*)in)[i];
        ushort4 o;
        o.x = f2bf(f.x); o.y = f2bf(f.y); o.z = f2bf(f.z); o.w = f2bf(f.w);
        ((ushort4*)out)[i] = o;
    }
}

// ---------------------------------------------------------------------------
// V transpose per head: vb[b*L+j][h*64+d] -> vt[(b*12+h)*64+d][j]
// ---------------------------------------------------------------------------
__global__ __launch_bounds__(256)
void vtrans_kernel(const ushort_t* __restrict__ vb, ushort_t* __restrict__ vt)
{
    const int bh = blockIdx.x;
    const int b = bh / kNH, h = bh - b * kNH;
    const int j0 = blockIdx.y * 64;
    __shared__ ushort_t T[64][72];

    const int tid = threadIdx.x;
    {
        const int jr = tid & 63;
        const int c0 = (tid >> 6) * 16;
        const ushort_t* sp = vb + (size_t)(b * kL + j0 + jr) * kD + h * kDK + c0;
        uint4 u0 = *(const uint4*)sp;
        uint4 u1 = *(const uint4*)(sp + 8);
        const ushort_t* e0 = (const ushort_t*)&u0;
        const ushort_t* e1 = (const ushort_t*)&u1;
        #pragma unroll
        for (int jj = 0; jj < 8; ++jj) {
            T[c0 + jj][jr]     = e0[jj];
            T[c0 + 8 + jj][jr] = e1[jj];
        }
    }
    __syncthreads();
    {
        const int dr = tid >> 2;
        const int jc = (tid & 3) * 16;
        ushort_t* dp = vt + (size_t)(bh * 64 + dr) * kL + j0 + jc;
        *(uint4*)dp       = *(const uint4*)&T[dr][jc];
        *(uint4*)(dp + 8) = *(const uint4*)&T[dr][jc + 8];
    }
}

// ---------------------------------------------------------------------------
// Relative-position bias table in MFMA-fragment order (see R5/R6 notes).
// ---------------------------------------------------------------------------
__global__ __launch_bounds__(256, 4)
void bias_kernel(const float* __restrict__ sx, const float* __restrict__ sy,
                 const float* __restrict__ P1, const float* __restrict__ pb1,
                 const float* __restrict__ P2, const float* __restrict__ pb2,
                 ushort_t* __restrict__ biasb)
{
    const int bid = blockIdx.x;
    const int b  = bid >> 10;
    const int qt = (bid >> 4) & 63;
    const int kt = bid & 15;
    const int tid = threadIdx.x;

    __shared__ float P[32][16];       // [u] = {A,B,C,0, W2[0..11]}
    __shared__ float pb2l[12];
    __shared__ float qxl[16], qyl[16], kxl[64], kyl[64];
    __shared__ ushort_t Btile[12 * 1024];   // 24 KB

    if (tid < 32) {
        P[tid][0] = P1[tid];
        P[tid][1] = P1[32 + tid];
        P[tid][2] = pb1[tid];
        P[tid][3] = 0.f;
    }
    for (int e = tid; e < 384; e += 256) P[e / 12][4 + e % 12] = P2[e];
    if (tid < 12) pb2l[tid] = pb2[tid];
    if (tid < 16) { qxl[tid] = sx[b * kL + qt * 16 + tid];
                    qyl[tid] = sy[b * kL + qt * 16 + tid]; }
    if (tid < 64) { kxl[tid] = sx[b * kL + kt * 64 + tid];
                    kyl[tid] = sy[b * kL + kt * 64 + tid]; }
    __syncthreads();

    const int ri = tid >> 4;
    const int fl = tid & 15;
    const int fq = ri >> 2, r = ri & 3;
    const int lane16 = fq * 16 + fl;
    const float xi = qxl[ri], yi = qyl[ri];

    float rx[4], ry[4];
    #pragma unroll
    for (int n = 0; n < 4; ++n) {
        const int cj = n * 16 + fl;
        rx[n] = fminf(fmaxf(xi - kxl[cj], -1000.f), 1000.f) * 1e-3f;
        ry[n] = fminf(fmaxf(yi - kyl[cj], -1000.f), 1000.f) * 1e-3f;
    }

    float acc[4][12] = {};
    #pragma unroll 4
    for (int u = 0; u < 32; ++u) {
        const float4 pc = *(const float4*)&P[u][0];
        const float4 w0 = *(const float4*)&P[u][4];
        const float4 w1 = *(const float4*)&P[u][8];
        const float4 w2 = *(const float4*)&P[u][12];
        float t[4];
        #pragma unroll
        for (int n = 0; n < 4; ++n)
            t[n] = fmaxf(fmaf(rx[n], pc.x, fmaf(ry[n], pc.y, pc.z)), 0.f);
        #pragma unroll
        for (int n = 0; n < 4; ++n) {
            acc[n][0]  = fmaf(t[n], w0.x, acc[n][0]);
            acc[n][1]  = fmaf(t[n], w0.y, acc[n][1]);
            acc[n][2]  = fmaf(t[n], w0.z, acc[n][2]);
            acc[n][3]  = fmaf(t[n], w0.w, acc[n][3]);
            acc[n][4]  = fmaf(t[n], w1.x, acc[n][4]);
            acc[n][5]  = fmaf(t[n], w1.y, acc[n][5]);
            acc[n][6]  = fmaf(t[n], w1.z, acc[n][6]);
            acc[n][7]  = fmaf(t[n], w1.w, acc[n][7]);
            acc[n][8]  = fmaf(t[n], w2.x, acc[n][8]);
            acc[n][9]  = fmaf(t[n], w2.y, acc[n][9]);
            acc[n][10] = fmaf(t[n], w2.z, acc[n][10]);
            acc[n][11] = fmaf(t[n], w2.w, acc[n][11]);
        }
    }

    #pragma unroll
    for (int h = 0; h < 12; ++h) {
        const float pb = pb2l[h];
        #pragma unroll
        for (int n = 0; n < 4; ++n)
            Btile[h * 1024 + lane16 * 16 + n * 4 + r] = f2bf(acc[n][h] + pb);
    }
    __syncthreads();

    #pragma unroll
    for (int i = 0; i < 6; ++i) {
        const int off = (i * 256 + tid) * 8;
        const int h = off >> 10;
        const int inner = off & 1023;
        ushort_t* dst = biasb +
            (((size_t)(b * kNH + h) * 64 + qt) * 16 + kt) * 1024 + inner;
        *(uint4*)dst = *(const uint4*)&Btile[off];
    }
}

// ---------------------------------------------------------------------------
// MFMA flash attention, split-K z=0..3 (256 keys / 4 tiles each).
// Online softmax (m,l), R6-proven body.  6144 one-wave blocks.
// __launch_bounds__(64,4): VGPR cap 128 >= the ~84 this body needs -> no
// spill (R8's (64,6) cap of 85 forced 400 MB of scratch spill traffic).
// At ~84 VGPR the HW grants 4 waves/SIMD (m69 occupancy steps).
// ---------------------------------------------------------------------------
__global__ __launch_bounds__(64, 4)
void attn_kernel(const ushort_t* __restrict__ qg, const ushort_t* __restrict__ kg,
                 const ushort_t* __restrict__ vt, const ushort_t* __restrict__ biasb,
                 ushort_t* __restrict__ p0, ushort_t* __restrict__ p1,
                 ushort_t* __restrict__ p2, ushort_t* __restrict__ p3,
                 float2* __restrict__ ml)
{
    const int bh = blockIdx.x;
    const int b  = bh / kNH, h = bh - b * kNH;
    const int qt = blockIdx.y;
    const int q0 = qt * 16;
    const int z  = blockIdx.z;
    const int lane = threadIdx.x;
    const int fl = lane & 15, fq = lane >> 4;

    __shared__ ushort_t Sp[16][72];

    const size_t qoff = (size_t)(b * kL + q0 + fl) * kD + h * kDK + fq * 8;
    const bf16x8 aq0 = *(const bf16x8*)(qg + qoff);
    const bf16x8 aq1 = *(const bf16x8*)(qg + qoff + 32);

    const ushort_t* kbase = kg + (size_t)(b * kL) * kD + h * kDK + fq * 8;
    const ushort_t* vbase = vt + (size_t)(bh * 64) * kL + fq * 8;
    const ushort_t* btile = biasb +
        ((size_t)(bh * 64 + qt) * 16 + z * 4) * 1024 + lane * 16;

    f32x4 accO[4] = {};
    float m_run[4] = {-INFINITY, -INFINITY, -INFINITY, -INFINITY};
    float l_run[4] = {};

    bf16x8 kc[4][2];
    uint4 bc0, bc1;
    {
        const int k0 = z * 256;
        #pragma unroll
        for (int n = 0; n < 4; ++n) {
            const ushort_t* kr = kbase + (size_t)(k0 + n * 16 + fl) * kD;
            kc[n][0] = *(const bf16x8*)kr;
            kc[n][1] = *(const bf16x8*)(kr + 32);
        }
        bc0 = *(const uint4*)btile;
        bc1 = *(const uint4*)(btile + 8);
    }

    #pragma unroll
    for (int t = 0; t < 4; ++t) {
        const int k0 = z * 256 + t * 64;

        bf16x8 vv[4][2];
        #pragma unroll
        for (int n = 0; n < 4; ++n) {
            const ushort_t* vr = vbase + (size_t)(n * 16 + fl) * kL + k0;
            vv[n][0] = *(const bf16x8*)vr;
            vv[n][1] = *(const bf16x8*)(vr + 32);
        }

        f32x4 S[4] = {};
        #pragma unroll
        for (int n = 0; n < 4; ++n) {
            S[n] = __builtin_amdgcn_mfma_f32_16x16x32_bf16(aq0, kc[n][0], S[n], 0, 0, 0);
            S[n] = __builtin_amdgcn_mfma_f32_16x16x32_bf16(aq1, kc[n][1], S[n], 0, 0, 0);
        }

        bf16x8 kn[4][2];
        uint4 bn0, bn1;
        if (t < 3) {
            #pragma unroll
            for (int n = 0; n < 4; ++n) {
                const ushort_t* kr = kbase + (size_t)(k0 + 64 + n * 16 + fl) * kD;
                kn[n][0] = *(const bf16x8*)kr;
                kn[n][1] = *(const bf16x8*)(kr + 32);
            }
            bn0 = *(const uint4*)(btile + (t + 1) * 1024);
            bn1 = *(const uint4*)(btile + (t + 1) * 1024 + 8);
        }

        ushort_t bu[16];
        *(uint4*)&bu[0] = bc0;
        *(uint4*)&bu[8] = bc1;
        #pragma unroll
        for (int n = 0; n < 4; ++n)
            #pragma unroll
            for (int r = 0; r < 4; ++r)
                S[n][r] = fmaf(S[n][r], 0.125f, bf2f(bu[n * 4 + r]));

        #pragma unroll
        for (int r = 0; r < 4; ++r) {
            float mx = fmaxf(fmaxf(S[0][r], S[1][r]), fmaxf(S[2][r], S[3][r]));
            mx = fmaxf(mx, __shfl_xor(mx, 1, 16));
            mx = fmaxf(mx, __shfl_xor(mx, 2, 16));
            mx = fmaxf(mx, __shfl_xor(mx, 4, 16));
            mx = fmaxf(mx, __shfl_xor(mx, 8, 16));
            const float mnew  = fmaxf(m_run[r], mx);
            const float alpha = __expf(m_run[r] - mnew);
            float ls = 0.f;
            #pragma unroll
            for (int n = 0; n < 4; ++n) {
                const float e = __expf(S[n][r] - mnew);
                S[n][r] = e;
                ls += e;
            }
            ls += __shfl_xor(ls, 1, 16);
            ls += __shfl_xor(ls, 2, 16);
            ls += __shfl_xor(ls, 4, 16);
            ls += __shfl_xor(ls, 8, 16);
            l_run[r] = l_run[r] * alpha + ls;
            m_run[r] = mnew;
            #pragma unroll
            for (int n = 0; n < 4; ++n) accO[n][r] *= alpha;
        }

        #pragma unroll
        for (int n = 0; n < 4; ++n)
            #pragma unroll
            for (int r = 0; r < 4; ++r)
                Sp[fq * 4 + r][n * 16 + fl] = f2bf(S[n][r]);
        __syncthreads();

        const bf16x8 ap0 = *(const bf16x8*)&Sp[fl][fq * 8];
        const bf16x8 ap1 = *(const bf16x8*)&Sp[fl][32 + fq * 8];
        #pragma unroll
        for (int n = 0; n < 4; ++n) {
            accO[n] = __builtin_amdgcn_mfma_f32_16x16x32_bf16(ap0, vv[n][0], accO[n], 0, 0, 0);
            accO[n] = __builtin_amdgcn_mfma_f32_16x16x32_bf16(ap1, vv[n][1], accO[n], 0, 0, 0);
        }
        __syncthreads();

        if (t < 3) {
            #pragma unroll
            for (int n = 0; n < 4; ++n) { kc[n][0] = kn[n][0]; kc[n][1] = kn[n][1]; }
            bc0 = bn0; bc1 = bn1;
        }
    }

    ushort_t* p = (z == 0) ? p0 : (z == 1) ? p1 : (z == 2) ? p2 : p3;
    float inv[4];
    #pragma unroll
    for (int r = 0; r < 4; ++r) inv[r] = 1.0f / l_run[r];
    #pragma unroll
    for (int n = 0; n < 4; ++n)
        #pragma unroll
        for (int r = 0; r < 4; ++r)
            p[(size_t)(b * kL + q0 + fq * 4 + r) * kD + h * kDK + n * 16 + fl] =
                f2bf(accO[n][r] * inv[r]);
    if (fl == 0) {
        #pragma unroll
        for (int r = 0; r < 4; ++r)
            ml[(size_t)z * kMLRows + bh * kL + q0 + fq * 4 + r] =
                make_float2(m_run[r], l_run[r]);
    }
}

// ---------------------------------------------------------------------------
// Combine the four attention splits: w_z ∝ e^{m_z - M} l_z.
// ---------------------------------------------------------------------------
__global__ __launch_bounds__(256)
void attn_combine_kernel(const ushort_t* __restrict__ p0, const ushort_t* __restrict__ p1,
                         const ushort_t* __restrict__ p2, const ushort_t* __restrict__ p3,
                         const float2* __restrict__ ml, ushort_t* __restrict__ out)
{
    const int tid = threadIdx.x;
    const int R = blockIdx.x * 32 + (tid >> 3);
    const int bh = R >> 10, i = R & 1023;
    const int b = bh / kNH, h = bh - b * kNH;

    const float2 s0 = ml[bh * kL + i];
    const float2 s1 = ml[kMLRows + bh * kL + i];
    const float2 s2 = ml[2 * kMLRows + bh * kL + i];
    const float2 s3 = ml[3 * kMLRows + bh * kL + i];
    const float M  = fmaxf(fmaxf(s0.x, s1.x), fmaxf(s2.x, s3.x));
    const float w0 = __expf(s0.x - M) * s0.y;
    const float w1 = __expf(s1.x - M) * s1.y;
    const float w2 = __expf(s2.x - M) * s2.y;
    const float w3 = __expf(s3.x - M) * s3.y;
    const float inv = 1.0f / (w0 + w1 + w2 + w3);
    const float c0 = w0 * inv, c1 = w1 * inv, c2 = w2 * inv, c3 = w3 * inv;

    const size_t base = (size_t)(b * kL + i) * kD + h * kDK + (tid & 7) * 8;
    uint4 u0 = *(const uint4*)(p0 + base);
    uint4 u1 = *(const uint4*)(p1 + base);
    uint4 u2 = *(const uint4*)(p2 + base);
    uint4 u3 = *(const uint4*)(p3 + base);
    const ushort_t* e0 = (const ushort_t*)&u0;
    const ushort_t* e1 = (const ushort_t*)&u1;
    const ushort_t* e2 = (const ushort_t*)&u2;
    const ushort_t* e3 = (const ushort_t*)&u3;
    ushort_t o[8];
    #pragma unroll
    for (int j = 0; j < 8; ++j)
        o[j] = f2bf(fmaf(c0, bf2f(e0[j]), fmaf(c1, bf2f(e1[j]),
                    fmaf(c2, bf2f(e2[j]), c3 * bf2f(e3[j])))));
    *(uint4*)(out + base) = *(const uint4*)o;
}

// ---------------------------------------------------------------------------
// Residual + split-K reduce + bias + LayerNorm.
// ---------------------------------------------------------------------------
template<int NPART, int DUAL>
__global__ __launch_bounds__(256)
void ln_kernel(const float* __restrict__ a, const float* __restrict__ parts,
               const float* __restrict__ bias,
               const float* __restrict__ g, const float* __restrict__ be,
               float* __restrict__ out, ushort_t* __restrict__ out_bf)
{
    const int row = blockIdx.x;
    const int tid = threadIdx.x;
    const float* pa = a + (size_t)row * kD;
    constexpr size_t NTOK = (size_t)kRows * kD;

    float v[3];
    float s = 0.f, sq = 0.f;
    #pragma unroll
    for (int i = 0; i < 3; ++i) {
        const int d = tid + i * 256;
        float t = pa[d] + bias[d];
        #pragma unroll
        for (int p = 0; p < NPART; ++p)
            t += parts[p * NTOK + (size_t)row * kD + d];
        v[i] = t;
        s  += t;
        sq += t * t;
    }
    #pragma unroll
    for (int off = 32; off > 0; off >>= 1) {
        s  += __shfl_down(s, off);
        sq += __shfl_down(sq, off);
    }
    __shared__ float bs[4], bq2[4];
    if ((tid & 63) == 0) { bs[tid >> 6] = s; bq2[tid >> 6] = sq; }
    __syncthreads();
    const float ts = bs[0] + bs[1] + bs[2] + bs[3];
    const float tq = bq2[0] + bq2[1] + bq2[2] + bq2[3];
    const float invn = 1.0f / (float)kD;
    const float mean = ts * invn;
    const float var  = tq * invn - mean * mean;
    const float rstd = rsqrtf(var + kEPS);

    float* po = out + (size_t)row * kD;
    #pragma unroll
    for (int i = 0; i < 3; ++i) {
        const int d = tid + i * 256;
        const float o = (v[i] - mean) * rstd * g[d] + be[d];
        po[d] = o;
        if (DUAL) out_bf[(size_t)row * kD + d] = f2bf(o);
    }
}

// ---------------------------------------------------------------------------
extern "C" void kernel_launch(void* const* d_in, const int* in_sizes, int n_in,
                              void* d_out, int out_size, void* d_ws, size_t ws_size,
                              hipStream_t stream)
{
    const float* src = (const float*)d_in[0];
    const float* sx  = (const float*)d_in[1];
    const float* sy  = (const float*)d_in[2];
    const float* Wq  = (const float*)d_in[3];  const float* bq  = (const float*)d_in[4];
    const float* Wk  = (const float*)d_in[5];  const float* bk  = (const float*)d_in[6];
    const float* Wv  = (const float*)d_in[7];  const float* bv  = (const float*)d_in[8];
    const float* Wo  = (const float*)d_in[9];  const float* bo  = (const float*)d_in[10];
    const float* P1  = (const float*)d_in[11]; const float* pb1 = (const float*)d_in[12];
    const float* P2  = (const float*)d_in[13]; const float* pb2 = (const float*)d_in[14];
    const float* W1  = (const float*)d_in[15]; const float* b1  = (const float*)d_in[16];
    const float* W2  = (const float*)d_in[17]; const float* b2  = (const float*)d_in[18];
    const float* g1  = (const float*)d_in[19]; const float* be1 = (const float*)d_in[20];
    const float* g2  = (const float*)d_in[21]; const float* be2 = (const float*)d_in[22];

    // ---- workspace arena (ushort units) ----
    constexpr size_t W768  = 768u * 768u;
    constexpr size_t W3072 = 768u * 3072u;
    constexpr size_t NTOK  = (size_t)kRows * kD;

    ushort_t* wsu = (ushort_t*)d_ws;
    ushort_t* wqT = wsu;                 // dead after QKV -> reused as ml buffer
    ushort_t* wkT = wqT + W768;
    ushort_t* wvT = wkT + W768;
    ushort_t* qb  = wvT + W768;          // Q -> (after combine) attn out -> xbf
    ushort_t* kb  = qb + NTOK;
    ushort_t* vb  = kb + NTOK;           // V -> attn partial O (split 1)
    ushort_t* sb  = vb + NTOK;           // src_bf -> attn partial O (split 0)
    ushort_t* vtb = sb + NTOK;
    ushort_t* biasb = vtb + NTOK;        // 50 MB bias; reused after attn:
    ushort_t* woT   = biasb;
    ushort_t* w1T   = woT + W768;
    ushort_t* w2T   = w1T + W3072;
    float*    xb    = (float*)(w2T + W3072);
    ushort_t* h1bf  = (ushort_t*)(xb + NTOK);
    float*    s2p   = (float*)h1bf;
    float*    ff2p  = (float*)(h1bf + 4 * NTOK);
    float2*   mlb   = (float2*)wqT;      // 786 KB (4 splits), alias of dead wqT
    ushort_t* p2b   = (ushort_t*)d_out;  // d_out (6.29 MB) = p2 + p3 scratch
    ushort_t* p3b   = p2b + NTOK;        //   (consumed by combine, before LN2 writes)
    ushort_t* xbf   = qb;

    const dim3 blk(256);

    WtArgs wa_early;
    wa_early.d[0] = { Wq, wqT, kD, kD };
    wa_early.d[1] = { Wk, wkT, kD, kD };
    wa_early.d[2] = { Wv, wvT, kD, kD };
    wt_kernel<<<dim3(144, 1, 3), blk, 0, stream>>>(wa_early);
    cvt_kernel<<<dim3((int)(NTOK / 4 / 256)), blk, 0, stream>>>(src, sb, (int)(NTOK / 4));
    bias_kernel<<<dim3(2048), blk, 0, stream>>>(sx, sy, P1, pb1, P2, pb2, biasb);

    gemm_qkv_kernel<<<dim3(kD / 128, kRows / 128, 3), blk, 0, stream>>>(
        sb, wqT, wkT, wvT, bq, bk, bv, qb, kb, vb);

    vtrans_kernel<<<dim3(2 * kNH, kL / 64), blk, 0, stream>>>(vb, vtb);

    // attention: split-K=4 (p0=sb, p1=vb, p2/p3=d_out scratch; ml in dead wqT)
    attn_kernel<<<dim3(2 * kNH, kL / 16, 4), dim3(64), 0, stream>>>(
        qb, kb, vtb, biasb, sb, vb, p2b, p3b, mlb);
    attn_combine_kernel<<<dim3(768), blk, 0, stream>>>(sb, vb, p2b, p3b, mlb, qb);

    WtArgs wa_late;
    wa_late.d[0] = { Wo, woT, kD,  kD  };
    wa_late.d[1] = { W1, w1T, kD,  kFF };
    wa_late.d[2] = { W2, w2T, kFF, kD  };
    wt_kernel<<<dim3(576, 1, 3), blk, 0, stream>>>(wa_late);

    gemm_splitk_kernel<<<dim3(kD / 128, kRows / 128, 2), blk, 0, stream>>>(
        qb, woT, s2p, kD, kD, kD / 2);

    ln_kernel<2, 1><<<dim3(kRows), blk, 0, stream>>>(src, s2p, bo, g1, be1, xb, xbf);

    gemm_kernel<1, 1><<<dim3(kFF / 128, kRows / 128), blk, 0, stream>>>(
        xbf, w1T, b1, h1bf, kFF, kD);

    gemm_splitk_kernel<<<dim3(kD / 128, kRows / 128, 3), blk, 0, stream>>>(
        h1bf, w2T, ff2p, kD, kFF, kFF / 3);

    ln_kernel<3, 0><<<dim3(kRows), blk, 0, stream>>>(xb, ff2p, b2, g2, be2,
                                                     (float*)d_out, nullptr);
}

// Round 10
// 312.995 us; speedup vs baseline: 1.4656x; 1.0689x over previous
//
#include <hip/hip_runtime.h>
#include <math.h>

typedef unsigned short ushort_t;
typedef __attribute__((ext_vector_type(8))) short bf16x8;
typedef __attribute__((ext_vector_type(4))) float f32x4;

constexpr int kD      = 768;
constexpr int kNH     = 12;
constexpr int kDK     = 64;
constexpr int kFF     = 3072;
constexpr int kL      = 1024;
constexpr int kRows   = 2048;     // B * L
constexpr float kEPS  = 1e-5f;
constexpr int kMLRows = 24 * kL;  // B*H*L q-rows

__device__ __forceinline__ ushort_t f2bf(float f) {
    union { float f; unsigned u; } v; v.f = f;
    unsigned r = (v.u + 0x7fffu + ((v.u >> 16) & 1u)) >> 16;
    return (ushort_t)r;
}
__device__ __forceinline__ float bf2f(ushort_t u) {
    union { unsigned u; float f; } v; v.u = ((unsigned)u) << 16; return v.f;
}

#define GL_LDS(gp, lp) __builtin_amdgcn_global_load_lds( \
    (const __attribute__((address_space(1))) void*)(gp), \
    (__attribute__((address_space(3))) void*)(lp), 16, 0, 0)

// ---------------------------------------------------------------------------
// bf16 MFMA GEMM (m97 structure): 128x128 tile, BK=32, 4 waves.
// ---------------------------------------------------------------------------
template<int RELU, int OUTBF, int ADDBIAS>
__device__ __forceinline__ void gemm_body(const ushort_t* __restrict__ A,
                                          const ushort_t* __restrict__ WT,
                                          const float* __restrict__ bias,
                                          void* __restrict__ Cout,
                                          int N, int K, int row0, int col0,
                                          int kbeg, int kend)
{
    __shared__ ushort_t lds[8192];
    ushort_t* As = lds;
    ushort_t* Bs = lds + 4096;

    const int tid  = threadIdx.x;
    const int lane = tid & 63;
    const int wave = tid >> 6;
    const int wrow = (wave & 1) * 64;
    const int wcol = (wave >> 1) * 64;

    const int srow = wave * 16 + (lane >> 2);
    const int sk   = (lane & 3) * 8;
    const ushort_t* ga0 = A  + (size_t)(row0 + srow)      * K + sk;
    const ushort_t* ga1 = A  + (size_t)(row0 + srow + 64) * K + sk;
    const ushort_t* gb0 = WT + (size_t)(col0 + srow)      * K + sk;
    const ushort_t* gb1 = WT + (size_t)(col0 + srow + 64) * K + sk;
    ushort_t* la0 = As + wave * 512;
    ushort_t* la1 = As + 2048 + wave * 512;
    ushort_t* lb0 = Bs + wave * 512;
    ushort_t* lb1 = Bs + 2048 + wave * 512;

    const int fl = lane & 15, fq = lane >> 4;
    const ushort_t* fa[4];
    const ushort_t* fb[4];
    #pragma unroll
    for (int i = 0; i < 4; ++i) {
        fa[i] = As + (wrow + i * 16 + fl) * 32 + fq * 8;
        fb[i] = Bs + (wcol + i * 16 + fl) * 32 + fq * 8;
    }

    f32x4 acc[4][4] = {};

    for (int k0 = kbeg; k0 < kend; k0 += 32) {
        __syncthreads();
        GL_LDS(ga0 + k0, la0);
        GL_LDS(ga1 + k0, la1);
        GL_LDS(gb0 + k0, lb0);
        GL_LDS(gb1 + k0, lb1);
        __syncthreads();

        bf16x8 av[4], bv[4];
        #pragma unroll
        for (int i = 0; i < 4; ++i) {
            av[i] = *(const bf16x8*)fa[i];
            bv[i] = *(const bf16x8*)fb[i];
        }
        #pragma unroll
        for (int mi = 0; mi < 4; ++mi)
            #pragma unroll
            for (int ni = 0; ni < 4; ++ni)
                acc[mi][ni] = __builtin_amdgcn_mfma_f32_16x16x32_bf16(
                    av[mi], bv[ni], acc[mi][ni], 0, 0, 0);
    }

    #pragma unroll
    for (int mi = 0; mi < 4; ++mi) {
        const int m = wrow + mi * 16 + fq * 4;
        #pragma unroll
        for (int ni = 0; ni < 4; ++ni) {
            const int n = wcol + ni * 16 + fl;
            const float bb = ADDBIAS ? bias[col0 + n] : 0.f;
            #pragma unroll
            for (int r = 0; r < 4; ++r) {
                float v = acc[mi][ni][r] + bb;
                if (RELU) v = fmaxf(v, 0.f);
                const size_t idx = (size_t)(row0 + m + r) * N + col0 + n;
                if (OUTBF) ((ushort_t*)Cout)[idx] = f2bf(v);
                else       ((float*)Cout)[idx]    = v;
            }
        }
    }
}

template<int RELU, int OUTBF>
__global__ __launch_bounds__(256)
void gemm_kernel(const ushort_t* __restrict__ A, const ushort_t* __restrict__ WT,
                 const float* __restrict__ bias, void* __restrict__ Cout,
                 int N, int K)
{
    gemm_body<RELU, OUTBF, 1>(A, WT, bias, Cout, N, K,
                              blockIdx.y * 128, blockIdx.x * 128, 0, K);
}

__global__ __launch_bounds__(256)
void gemm_splitk_kernel(const ushort_t* __restrict__ A, const ushort_t* __restrict__ WT,
                        float* __restrict__ parts, int N, int K, int kslice)
{
    const int z = blockIdx.z;
    float* out = parts + (size_t)z * kRows * N;
    gemm_body<0, 0, 0>(A, WT, nullptr, out, N, K,
                       blockIdx.y * 128, blockIdx.x * 128, z * kslice, (z + 1) * kslice);
}

__global__ __launch_bounds__(256)
void gemm_qkv_kernel(const ushort_t* __restrict__ A,
                     const ushort_t* wq, const ushort_t* wk, const ushort_t* wv,
                     const float* bq, const float* bk, const float* bv,
                     ushort_t* q, ushort_t* k, ushort_t* v)
{
    const ushort_t* WT; const float* bias; ushort_t* out;
    if (blockIdx.z == 0)      { WT = wq; bias = bq; out = q; }
    else if (blockIdx.z == 1) { WT = wk; bias = bk; out = k; }
    else                      { WT = wv; bias = bv; out = v; }
    gemm_body<0, 1, 1>(A, WT, bias, out, kD, kD,
                       blockIdx.y * 128, blockIdx.x * 128, 0, kD);
}

// ---------------------------------------------------------------------------
// Weight transpose + fp32->bf16:  W[K][N] -> WT[N][K] bf16.
// ---------------------------------------------------------------------------
struct WtDesc { const float* src; ushort_t* dst; int K; int N; };
struct WtArgs { WtDesc d[3]; };

__global__ __launch_bounds__(256)
void wt_kernel(WtArgs args)
{
    const WtDesc w = args.d[blockIdx.z];
    const int ktiles = w.K >> 6;
    const int kt = (blockIdx.x % ktiles) * 64;
    const int nt = (blockIdx.x / ktiles) * 64;
    if (nt >= w.N) return;

    __shared__ float T[64][65];
    const int tid = threadIdx.x;
    #pragma unroll
    for (int i = 0; i < 4; ++i) {
        const int e = tid + i * 256;
        const int r = e >> 4;
        const int c = (e & 15) * 4;
        const float4 f = *(const float4*)&w.src[(size_t)(kt + r) * w.N + nt + c];
        T[c + 0][r] = f.x; T[c + 1][r] = f.y; T[c + 2][r] = f.z; T[c + 3][r] = f.w;
    }
    __syncthreads();
    #pragma unroll
    for (int i = 0; i < 4; ++i) {
        const int e = tid + i * 256;
        const int n = e >> 4;
        const int kc = (e & 15) * 4;
        ushort4 o;
        o.x = f2bf(T[n][kc + 0]); o.y = f2bf(T[n][kc + 1]);
        o.z = f2bf(T[n][kc + 2]); o.w = f2bf(T[n][kc + 3]);
        *(ushort4*)&w.dst[(size_t)(nt + n) * w.K + kt + kc] = o;
    }
}

// fp32 -> bf16 elementwise
__global__ __launch_bounds__(256)
void cvt_kernel(const float* __restrict__ in, ushort_t* __restrict__ out, int n4)
{
    const int i = blockIdx.x * 256 + threadIdx.x;
    if (i < n4) {
        const float4 f = ((const float4*)in)[i];
        ushort4 o;
        o.x = f2bf(f.x); o.y = f2bf(f.y); o.z = f2bf(f.z); o.w = f2bf(f.w);
        ((ushort4*)out)[i] = o;
    }
}

// ---------------------------------------------------------------------------
// V transpose per head: vb[b*L+j][h*64+d] -> vt[(b*12+h)*64+d][j]
// ---------------------------------------------------------------------------
__global__ __launch_bounds__(256)
void vtrans_kernel(const ushort_t* __restrict__ vb, ushort_t* __restrict__ vt)
{
    const int bh = blockIdx.x;
    const int b = bh / kNH, h = bh - b * kNH;
    const int j0 = blockIdx.y * 64;
    __shared__ ushort_t T[64][72];

    const int tid = threadIdx.x;
    {
        const int jr = tid & 63;
        const int c0 = (tid >> 6) * 16;
        const ushort_t* sp = vb + (size_t)(b * kL + j0 + jr) * kD + h * kDK + c0;
        uint4 u0 = *(const uint4*)sp;
        uint4 u1 = *(const uint4*)(sp + 8);
        const ushort_t* e0 = (const ushort_t*)&u0;
        const ushort_t* e1 = (const ushort_t*)&u1;
        #pragma unroll
        for (int jj = 0; jj < 8; ++jj) {
            T[c0 + jj][jr]     = e0[jj];
            T[c0 + 8 + jj][jr] = e1[jj];
        }
    }
    __syncthreads();
    {
        const int dr = tid >> 2;
        const int jc = (tid & 3) * 16;
        ushort_t* dp = vt + (size_t)(bh * 64 + dr) * kL + j0 + jc;
        *(uint4*)dp       = *(const uint4*)&T[dr][jc];
        *(uint4*)(dp + 8) = *(const uint4*)&T[dr][jc + 8];
    }
}

// ---------------------------------------------------------------------------
// Relative-position bias table in MFMA-fragment order (see R5/R6 notes).
// ---------------------------------------------------------------------------
__global__ __launch_bounds__(256, 4)
void bias_kernel(const float* __restrict__ sx, const float* __restrict__ sy,
                 const float* __restrict__ P1, const float* __restrict__ pb1,
                 const float* __restrict__ P2, const float* __restrict__ pb2,
                 ushort_t* __restrict__ biasb)
{
    const int bid = blockIdx.x;
    const int b  = bid >> 10;
    const int qt = (bid >> 4) & 63;
    const int kt = bid & 15;
    const int tid = threadIdx.x;

    __shared__ float P[32][16];       // [u] = {A,B,C,0, W2[0..11]}
    __shared__ float pb2l[12];
    __shared__ float qxl[16], qyl[16], kxl[64], kyl[64];
    __shared__ ushort_t Btile[12 * 1024];   // 24 KB

    if (tid < 32) {
        P[tid][0] = P1[tid];
        P[tid][1] = P1[32 + tid];
        P[tid][2] = pb1[tid];
        P[tid][3] = 0.f;
    }
    for (int e = tid; e < 384; e += 256) P[e / 12][4 + e % 12] = P2[e];
    if (tid < 12) pb2l[tid] = pb2[tid];
    if (tid < 16) { qxl[tid] = sx[b * kL + qt * 16 + tid];
                    qyl[tid] = sy[b * kL + qt * 16 + tid]; }
    if (tid < 64) { kxl[tid] = sx[b * kL + kt * 64 + tid];
                    kyl[tid] = sy[b * kL + kt * 64 + tid]; }
    __syncthreads();

    const int ri = tid >> 4;
    const int fl = tid & 15;
    const int fq = ri >> 2, r = ri & 3;
    const int lane16 = fq * 16 + fl;
    const float xi = qxl[ri], yi = qyl[ri];

    float rx[4], ry[4];
    #pragma unroll
    for (int n = 0; n < 4; ++n) {
        const int cj = n * 16 + fl;
        rx[n] = fminf(fmaxf(xi - kxl[cj], -1000.f), 1000.f) * 1e-3f;
        ry[n] = fminf(fmaxf(yi - kyl[cj], -1000.f), 1000.f) * 1e-3f;
    }

    float acc[4][12] = {};
    #pragma unroll 4
    for (int u = 0; u < 32; ++u) {
        const float4 pc = *(const float4*)&P[u][0];
        const float4 w0 = *(const float4*)&P[u][4];
        const float4 w1 = *(const float4*)&P[u][8];
        const float4 w2 = *(const float4*)&P[u][12];
        float t[4];
        #pragma unroll
        for (int n = 0; n < 4; ++n)
            t[n] = fmaxf(fmaf(rx[n], pc.x, fmaf(ry[n], pc.y, pc.z)), 0.f);
        #pragma unroll
        for (int n = 0; n < 4; ++n) {
            acc[n][0]  = fmaf(t[n], w0.x, acc[n][0]);
            acc[n][1]  = fmaf(t[n], w0.y, acc[n][1]);
            acc[n][2]  = fmaf(t[n], w0.z, acc[n][2]);
            acc[n][3]  = fmaf(t[n], w0.w, acc[n][3]);
            acc[n][4]  = fmaf(t[n], w1.x, acc[n][4]);
            acc[n][5]  = fmaf(t[n], w1.y, acc[n][5]);
            acc[n][6]  = fmaf(t[n], w1.z, acc[n][6]);
            acc[n][7]  = fmaf(t[n], w1.w, acc[n][7]);
            acc[n][8]  = fmaf(t[n], w2.x, acc[n][8]);
            acc[n][9]  = fmaf(t[n], w2.y, acc[n][9]);
            acc[n][10] = fmaf(t[n], w2.z, acc[n][10]);
            acc[n][11] = fmaf(t[n], w2.w, acc[n][11]);
        }
    }

    #pragma unroll
    for (int h = 0; h < 12; ++h) {
        const float pb = pb2l[h];
        #pragma unroll
        for (int n = 0; n < 4; ++n)
            Btile[h * 1024 + lane16 * 16 + n * 4 + r] = f2bf(acc[n][h] + pb);
    }
    __syncthreads();

    #pragma unroll
    for (int i = 0; i < 6; ++i) {
        const int off = (i * 256 + tid) * 8;
        const int h = off >> 10;
        const int inner = off & 1023;
        ushort_t* dst = biasb +
            (((size_t)(b * kNH + h) * 64 + qt) * 16 + kt) * 1024 + inner;
        *(uint4*)dst = *(const uint4*)&Btile[off];
    }
}

// ---------------------------------------------------------------------------
// MFMA flash attention, split-K z=0..3 (256 keys / 4 tiles each).
// Online softmax (m,l), R6-proven body.  6144 one-wave blocks.
// __launch_bounds__(64,3): the ONLY spill-free bound measured for this body
// (R6/R7: 80-84 arch VGPRs, WRITE ~7-13 MB).  The min-waves arg caps the
// TOTAL unified VGPR file and the compiler splits arch/acc: (64,4)->64 arch
// (spill, 122 MB scratch traffic, R9), (64,6)->40 arch (398 MB, R8).
// ---------------------------------------------------------------------------
__global__ __launch_bounds__(64, 3)
void attn_kernel(const ushort_t* __restrict__ qg, const ushort_t* __restrict__ kg,
                 const ushort_t* __restrict__ vt, const ushort_t* __restrict__ biasb,
                 ushort_t* __restrict__ p0, ushort_t* __restrict__ p1,
                 ushort_t* __restrict__ p2, ushort_t* __restrict__ p3,
                 float2* __restrict__ ml)
{
    const int bh = blockIdx.x;
    const int b  = bh / kNH, h = bh - b * kNH;
    const int qt = blockIdx.y;
    const int q0 = qt * 16;
    const int z  = blockIdx.z;
    const int lane = threadIdx.x;
    const int fl = lane & 15, fq = lane >> 4;

    __shared__ ushort_t Sp[16][72];

    const size_t qoff = (size_t)(b * kL + q0 + fl) * kD + h * kDK + fq * 8;
    const bf16x8 aq0 = *(const bf16x8*)(qg + qoff);
    const bf16x8 aq1 = *(const bf16x8*)(qg + qoff + 32);

    const ushort_t* kbase = kg + (size_t)(b * kL) * kD + h * kDK + fq * 8;
    const ushort_t* vbase = vt + (size_t)(bh * 64) * kL + fq * 8;
    const ushort_t* btile = biasb +
        ((size_t)(bh * 64 + qt) * 16 + z * 4) * 1024 + lane * 16;

    f32x4 accO[4] = {};
    float m_run[4] = {-INFINITY, -INFINITY, -INFINITY, -INFINITY};
    float l_run[4] = {};

    bf16x8 kc[4][2];
    uint4 bc0, bc1;
    {
        const int k0 = z * 256;
        #pragma unroll
        for (int n = 0; n < 4; ++n) {
            const ushort_t* kr = kbase + (size_t)(k0 + n * 16 + fl) * kD;
            kc[n][0] = *(const bf16x8*)kr;
            kc[n][1] = *(const bf16x8*)(kr + 32);
        }
        bc0 = *(const uint4*)btile;
        bc1 = *(const uint4*)(btile + 8);
    }

    #pragma unroll
    for (int t = 0; t < 4; ++t) {
        const int k0 = z * 256 + t * 64;

        bf16x8 vv[4][2];
        #pragma unroll
        for (int n = 0; n < 4; ++n) {
            const ushort_t* vr = vbase + (size_t)(n * 16 + fl) * kL + k0;
            vv[n][0] = *(const bf16x8*)vr;
            vv[n][1] = *(const bf16x8*)(vr + 32);
        }

        f32x4 S[4] = {};
        #pragma unroll
        for (int n = 0; n < 4; ++n) {
            S[n] = __builtin_amdgcn_mfma_f32_16x16x32_bf16(aq0, kc[n][0], S[n], 0, 0, 0);
            S[n] = __builtin_amdgcn_mfma_f32_16x16x32_bf16(aq1, kc[n][1], S[n], 0, 0, 0);
        }

        bf16x8 kn[4][2];
        uint4 bn0, bn1;
        if (t < 3) {
            #pragma unroll
            for (int n = 0; n < 4; ++n) {
                const ushort_t* kr = kbase + (size_t)(k0 + 64 + n * 16 + fl) * kD;
                kn[n][0] = *(const bf16x8*)kr;
                kn[n][1] = *(const bf16x8*)(kr + 32);
            }
            bn0 = *(const uint4*)(btile + (t + 1) * 1024);
            bn1 = *(const uint4*)(btile + (t + 1) * 1024 + 8);
        }

        ushort_t bu[16];
        *(uint4*)&bu[0] = bc0;
        *(uint4*)&bu[8] = bc1;
        #pragma unroll
        for (int n = 0; n < 4; ++n)
            #pragma unroll
            for (int r = 0; r < 4; ++r)
                S[n][r] = fmaf(S[n][r], 0.125f, bf2f(bu[n * 4 + r]));

        #pragma unroll
        for (int r = 0; r < 4; ++r) {
            float mx = fmaxf(fmaxf(S[0][r], S[1][r]), fmaxf(S[2][r], S[3][r]));
            mx = fmaxf(mx, __shfl_xor(mx, 1, 16));
            mx = fmaxf(mx, __shfl_xor(mx, 2, 16));
            mx = fmaxf(mx, __shfl_xor(mx, 4, 16));
            mx = fmaxf(mx, __shfl_xor(mx, 8, 16));
            const float mnew  = fmaxf(m_run[r], mx);
            const float alpha = __expf(m_run[r] - mnew);
            float ls = 0.f;
            #pragma unroll
            for (int n = 0; n < 4; ++n) {
                const float e = __expf(S[n][r] - mnew);
                S[n][r] = e;
                ls += e;
            }
            ls += __shfl_xor(ls, 1, 16);
            ls += __shfl_xor(ls, 2, 16);
            ls += __shfl_xor(ls, 4, 16);
            ls += __shfl_xor(ls, 8, 16);
            l_run[r] = l_run[r] * alpha + ls;
            m_run[r] = mnew;
            #pragma unroll
            for (int n = 0; n < 4; ++n) accO[n][r] *= alpha;
        }

        #pragma unroll
        for (int n = 0; n < 4; ++n)
            #pragma unroll
            for (int r = 0; r < 4; ++r)
                Sp[fq * 4 + r][n * 16 + fl] = f2bf(S[n][r]);
        __syncthreads();

        const bf16x8 ap0 = *(const bf16x8*)&Sp[fl][fq * 8];
        const bf16x8 ap1 = *(const bf16x8*)&Sp[fl][32 + fq * 8];
        #pragma unroll
        for (int n = 0; n < 4; ++n) {
            accO[n] = __builtin_amdgcn_mfma_f32_16x16x32_bf16(ap0, vv[n][0], accO[n], 0, 0, 0);
            accO[n] = __builtin_amdgcn_mfma_f32_16x16x32_bf16(ap1, vv[n][1], accO[n], 0, 0, 0);
        }
        __syncthreads();

        if (t < 3) {
            #pragma unroll
            for (int n = 0; n < 4; ++n) { kc[n][0] = kn[n][0]; kc[n][1] = kn[n][1]; }
            bc0 = bn0; bc1 = bn1;
        }
    }

    ushort_t* p = (z == 0) ? p0 : (z == 1) ? p1 : (z == 2) ? p2 : p3;
    float inv[4];
    #pragma unroll
    for (int r = 0; r < 4; ++r) inv[r] = 1.0f / l_run[r];
    #pragma unroll
    for (int n = 0; n < 4; ++n)
        #pragma unroll
        for (int r = 0; r < 4; ++r)
            p[(size_t)(b * kL + q0 + fq * 4 + r) * kD + h * kDK + n * 16 + fl] =
                f2bf(accO[n][r] * inv[r]);
    if (fl == 0) {
        #pragma unroll
        for (int r = 0; r < 4; ++r)
            ml[(size_t)z * kMLRows + bh * kL + q0 + fq * 4 + r] =
                make_float2(m_run[r], l_run[r]);
    }
}

// ---------------------------------------------------------------------------
// Combine the four attention splits: w_z ∝ e^{m_z - M} l_z.
// ---------------------------------------------------------------------------
__global__ __launch_bounds__(256)
void attn_combine_kernel(const ushort_t* __restrict__ p0, const ushort_t* __restrict__ p1,
                         const ushort_t* __restrict__ p2, const ushort_t* __restrict__ p3,
                         const float2* __restrict__ ml, ushort_t* __restrict__ out)
{
    const int tid = threadIdx.x;
    const int R = blockIdx.x * 32 + (tid >> 3);
    const int bh = R >> 10, i = R & 1023;
    const int b = bh / kNH, h = bh - b * kNH;

    const float2 s0 = ml[bh * kL + i];
    const float2 s1 = ml[kMLRows + bh * kL + i];
    const float2 s2 = ml[2 * kMLRows + bh * kL + i];
    const float2 s3 = ml[3 * kMLRows + bh * kL + i];
    const float M  = fmaxf(fmaxf(s0.x, s1.x), fmaxf(s2.x, s3.x));
    const float w0 = __expf(s0.x - M) * s0.y;
    const float w1 = __expf(s1.x - M) * s1.y;
    const float w2 = __expf(s2.x - M) * s2.y;
    const float w3 = __expf(s3.x - M) * s3.y;
    const float inv = 1.0f / (w0 + w1 + w2 + w3);
    const float c0 = w0 * inv, c1 = w1 * inv, c2 = w2 * inv, c3 = w3 * inv;

    const size_t base = (size_t)(b * kL + i) * kD + h * kDK + (tid & 7) * 8;
    uint4 u0 = *(const uint4*)(p0 + base);
    uint4 u1 = *(const uint4*)(p1 + base);
    uint4 u2 = *(const uint4*)(p2 + base);
    uint4 u3 = *(const uint4*)(p3 + base);
    const ushort_t* e0 = (const ushort_t*)&u0;
    const ushort_t* e1 = (const ushort_t*)&u1;
    const ushort_t* e2 = (const ushort_t*)&u2;
    const ushort_t* e3 = (const ushort_t*)&u3;
    ushort_t o[8];
    #pragma unroll
    for (int j = 0; j < 8; ++j)
        o[j] = f2bf(fmaf(c0, bf2f(e0[j]), fmaf(c1, bf2f(e1[j]),
                    fmaf(c2, bf2f(e2[j]), c3 * bf2f(e3[j])))));
    *(uint4*)(out + base) = *(const uint4*)o;
}

// ---------------------------------------------------------------------------
// Residual + split-K reduce + bias + LayerNorm.
// ---------------------------------------------------------------------------
template<int NPART, int DUAL>
__global__ __launch_bounds__(256)
void ln_kernel(const float* __restrict__ a, const float* __restrict__ parts,
               const float* __restrict__ bias,
               const float* __restrict__ g, const float* __restrict__ be,
               float* __restrict__ out, ushort_t* __restrict__ out_bf)
{
    const int row = blockIdx.x;
    const int tid = threadIdx.x;
    const float* pa = a + (size_t)row * kD;
    constexpr size_t NTOK = (size_t)kRows * kD;

    float v[3];
    float s = 0.f, sq = 0.f;
    #pragma unroll
    for (int i = 0; i < 3; ++i) {
        const int d = tid + i * 256;
        float t = pa[d] + bias[d];
        #pragma unroll
        for (int p = 0; p < NPART; ++p)
            t += parts[p * NTOK + (size_t)row * kD + d];
        v[i] = t;
        s  += t;
        sq += t * t;
    }
    #pragma unroll
    for (int off = 32; off > 0; off >>= 1) {
        s  += __shfl_down(s, off);
        sq += __shfl_down(sq, off);
    }
    __shared__ float bs[4], bq2[4];
    if ((tid & 63) == 0) { bs[tid >> 6] = s; bq2[tid >> 6] = sq; }
    __syncthreads();
    const float ts = bs[0] + bs[1] + bs[2] + bs[3];
    const float tq = bq2[0] + bq2[1] + bq2[2] + bq2[3];
    const float invn = 1.0f / (float)kD;
    const float mean = ts * invn;
    const float var  = tq * invn - mean * mean;
    const float rstd = rsqrtf(var + kEPS);

    float* po = out + (size_t)row * kD;
    #pragma unroll
    for (int i = 0; i < 3; ++i) {
        const int d = tid + i * 256;
        const float o = (v[i] - mean) * rstd * g[d] + be[d];
        po[d] = o;
        if (DUAL) out_bf[(size_t)row * kD + d] = f2bf(o);
    }
}

// ---------------------------------------------------------------------------
extern "C" void kernel_launch(void* const* d_in, const int* in_sizes, int n_in,
                              void* d_out, int out_size, void* d_ws, size_t ws_size,
                              hipStream_t stream)
{
    const float* src = (const float*)d_in[0];
    const float* sx  = (const float*)d_in[1];
    const float* sy  = (const float*)d_in[2];
    const float* Wq  = (const float*)d_in[3];  const float* bq  = (const float*)d_in[4];
    const float* Wk  = (const float*)d_in[5];  const float* bk  = (const float*)d_in[6];
    const float* Wv  = (const float*)d_in[7];  const float* bv  = (const float*)d_in[8];
    const float* Wo  = (const float*)d_in[9];  const float* bo  = (const float*)d_in[10];
    const float* P1  = (const float*)d_in[11]; const float* pb1 = (const float*)d_in[12];
    const float* P2  = (const float*)d_in[13]; const float* pb2 = (const float*)d_in[14];
    const float* W1  = (const float*)d_in[15]; const float* b1  = (const float*)d_in[16];
    const float* W2  = (const float*)d_in[17]; const float* b2  = (const float*)d_in[18];
    const float* g1  = (const float*)d_in[19]; const float* be1 = (const float*)d_in[20];
    const float* g2  = (const float*)d_in[21]; const float* be2 = (const float*)d_in[22];

    // ---- workspace arena (ushort units) ----
    constexpr size_t W768  = 768u * 768u;
    constexpr size_t W3072 = 768u * 3072u;
    constexpr size_t NTOK  = (size_t)kRows * kD;

    ushort_t* wsu = (ushort_t*)d_ws;
    ushort_t* wqT = wsu;                 // dead after QKV -> reused as ml buffer
    ushort_t* wkT = wqT + W768;
    ushort_t* wvT = wkT + W768;
    ushort_t* qb  = wvT + W768;          // Q -> (after combine) attn out -> xbf
    ushort_t* kb  = qb + NTOK;
    ushort_t* vb  = kb + NTOK;           // V -> attn partial O (split 1)
    ushort_t* sb  = vb + NTOK;           // src_bf -> attn partial O (split 0)
    ushort_t* vtb = sb + NTOK;
    ushort_t* biasb = vtb + NTOK;        // 50 MB bias; reused after attn:
    ushort_t* woT   = biasb;
    ushort_t* w1T   = woT + W768;
    ushort_t* w2T   = w1T + W3072;
    float*    xb    = (float*)(w2T + W3072);
    ushort_t* h1bf  = (ushort_t*)(xb + NTOK);
    float*    s2p   = (float*)h1bf;
    float*    ff2p  = (float*)(h1bf + 4 * NTOK);
    float2*   mlb   = (float2*)wqT;      // 786 KB (4 splits), alias of dead wqT
    ushort_t* p2b   = (ushort_t*)d_out;  // d_out (6.29 MB) = p2 + p3 scratch
    ushort_t* p3b   = p2b + NTOK;        //   (consumed by combine, before LN2 writes)
    ushort_t* xbf   = qb;

    const dim3 blk(256);

    WtArgs wa_early;
    wa_early.d[0] = { Wq, wqT, kD, kD };
    wa_early.d[1] = { Wk, wkT, kD, kD };
    wa_early.d[2] = { Wv, wvT, kD, kD };
    wt_kernel<<<dim3(144, 1, 3), blk, 0, stream>>>(wa_early);
    cvt_kernel<<<dim3((int)(NTOK / 4 / 256)), blk, 0, stream>>>(src, sb, (int)(NTOK / 4));
    bias_kernel<<<dim3(2048), blk, 0, stream>>>(sx, sy, P1, pb1, P2, pb2, biasb);

    gemm_qkv_kernel<<<dim3(kD / 128, kRows / 128, 3), blk, 0, stream>>>(
        sb, wqT, wkT, wvT, bq, bk, bv, qb, kb, vb);

    vtrans_kernel<<<dim3(2 * kNH, kL / 64), blk, 0, stream>>>(vb, vtb);

    // attention: split-K=4 (p0=sb, p1=vb, p2/p3=d_out scratch; ml in dead wqT)
    attn_kernel<<<dim3(2 * kNH, kL / 16, 4), dim3(64), 0, stream>>>(
        qb, kb, vtb, biasb, sb, vb, p2b, p3b, mlb);
    attn_combine_kernel<<<dim3(768), blk, 0, stream>>>(sb, vb, p2b, p3b, mlb, qb);

    WtArgs wa_late;
    wa_late.d[0] = { Wo, woT, kD,  kD  };
    wa_late.d[1] = { W1, w1T, kD,  kFF };
    wa_late.d[2] = { W2, w2T, kFF, kD  };
    wt_kernel<<<dim3(576, 1, 3), blk, 0, stream>>>(wa_late);

    gemm_splitk_kernel<<<dim3(kD / 128, kRows / 128, 2), blk, 0, stream>>>(
        qb, woT, s2p, kD, kD, kD / 2);

    ln_kernel<2, 1><<<dim3(kRows), blk, 0, stream>>>(src, s2p, bo, g1, be1, xb, xbf);

    gemm_kernel<1, 1><<<dim3(kFF / 128, kRows / 128), blk, 0, stream>>>(
        xbf, w1T, b1, h1bf, kFF, kD);

    gemm_splitk_kernel<<<dim3(kD / 128, kRows / 128, 3), blk, 0, stream>>>(
        h1bf, w2T, ff2p, kD, kFF, kFF / 3);

    ln_kernel<3, 0><<<dim3(kRows), blk, 0, stream>>>(xb, ff2p, b2, g2, be2,
                                                     (float*)d_out, nullptr);
}

// Round 11
// 298.625 us; speedup vs baseline: 1.5361x; 1.0481x over previous
//
#include <hip/hip_runtime.h>
#include <math.h>

typedef unsigned short ushort_t;
typedef __attribute__((ext_vector_type(8))) short bf16x8;
typedef __attribute__((ext_vector_type(4))) float f32x4;

constexpr int kD      = 768;
constexpr int kNH     = 12;
constexpr int kDK     = 64;
constexpr int kFF     = 3072;
constexpr int kL      = 1024;
constexpr int kRows   = 2048;     // B * L
constexpr float kEPS  = 1e-5f;

__device__ __forceinline__ ushort_t f2bf(float f) {
    union { float f; unsigned u; } v; v.f = f;
    unsigned r = (v.u + 0x7fffu + ((v.u >> 16) & 1u)) >> 16;
    return (ushort_t)r;
}
__device__ __forceinline__ float bf2f(ushort_t u) {
    union { unsigned u; float f; } v; v.u = ((unsigned)u) << 16; return v.f;
}

#define GL_LDS(gp, lp) __builtin_amdgcn_global_load_lds( \
    (const __attribute__((address_space(1))) void*)(gp), \
    (__attribute__((address_space(3))) void*)(lp), 16, 0, 0)

// ---------------------------------------------------------------------------
// bf16 MFMA GEMM (m97 structure): 128x128 tile, BK=32, 4 waves.
// ---------------------------------------------------------------------------
template<int RELU, int OUTBF, int ADDBIAS>
__device__ __forceinline__ void gemm_body(const ushort_t* __restrict__ A,
                                          const ushort_t* __restrict__ WT,
                                          const float* __restrict__ bias,
                                          void* __restrict__ Cout,
                                          int N, int K, int row0, int col0,
                                          int kbeg, int kend)
{
    __shared__ ushort_t lds[8192];
    ushort_t* As = lds;
    ushort_t* Bs = lds + 4096;

    const int tid  = threadIdx.x;
    const int lane = tid & 63;
    const int wave = tid >> 6;
    const int wrow = (wave & 1) * 64;
    const int wcol = (wave >> 1) * 64;

    const int srow = wave * 16 + (lane >> 2);
    const int sk   = (lane & 3) * 8;
    const ushort_t* ga0 = A  + (size_t)(row0 + srow)      * K + sk;
    const ushort_t* ga1 = A  + (size_t)(row0 + srow + 64) * K + sk;
    const ushort_t* gb0 = WT + (size_t)(col0 + srow)      * K + sk;
    const ushort_t* gb1 = WT + (size_t)(col0 + srow + 64) * K + sk;
    ushort_t* la0 = As + wave * 512;
    ushort_t* la1 = As + 2048 + wave * 512;
    ushort_t* lb0 = Bs + wave * 512;
    ushort_t* lb1 = Bs + 2048 + wave * 512;

    const int fl = lane & 15, fq = lane >> 4;
    const ushort_t* fa[4];
    const ushort_t* fb[4];
    #pragma unroll
    for (int i = 0; i < 4; ++i) {
        fa[i] = As + (wrow + i * 16 + fl) * 32 + fq * 8;
        fb[i] = Bs + (wcol + i * 16 + fl) * 32 + fq * 8;
    }

    f32x4 acc[4][4] = {};

    for (int k0 = kbeg; k0 < kend; k0 += 32) {
        __syncthreads();
        GL_LDS(ga0 + k0, la0);
        GL_LDS(ga1 + k0, la1);
        GL_LDS(gb0 + k0, lb0);
        GL_LDS(gb1 + k0, lb1);
        __syncthreads();

        bf16x8 av[4], bv[4];
        #pragma unroll
        for (int i = 0; i < 4; ++i) {
            av[i] = *(const bf16x8*)fa[i];
            bv[i] = *(const bf16x8*)fb[i];
        }
        #pragma unroll
        for (int mi = 0; mi < 4; ++mi)
            #pragma unroll
            for (int ni = 0; ni < 4; ++ni)
                acc[mi][ni] = __builtin_amdgcn_mfma_f32_16x16x32_bf16(
                    av[mi], bv[ni], acc[mi][ni], 0, 0, 0);
    }

    #pragma unroll
    for (int mi = 0; mi < 4; ++mi) {
        const int m = wrow + mi * 16 + fq * 4;
        #pragma unroll
        for (int ni = 0; ni < 4; ++ni) {
            const int n = wcol + ni * 16 + fl;
            const float bb = ADDBIAS ? bias[col0 + n] : 0.f;
            #pragma unroll
            for (int r = 0; r < 4; ++r) {
                float v = acc[mi][ni][r] + bb;
                if (RELU) v = fmaxf(v, 0.f);
                const size_t idx = (size_t)(row0 + m + r) * N + col0 + n;
                if (OUTBF) ((ushort_t*)Cout)[idx] = f2bf(v);
                else       ((float*)Cout)[idx]    = v;
            }
        }
    }
}

template<int RELU, int OUTBF>
__global__ __launch_bounds__(256)
void gemm_kernel(const ushort_t* __restrict__ A, const ushort_t* __restrict__ WT,
                 const float* __restrict__ bias, void* __restrict__ Cout,
                 int N, int K)
{
    gemm_body<RELU, OUTBF, 1>(A, WT, bias, Cout, N, K,
                              blockIdx.y * 128, blockIdx.x * 128, 0, K);
}

__global__ __launch_bounds__(256)
void gemm_splitk_kernel(const ushort_t* __restrict__ A, const ushort_t* __restrict__ WT,
                        float* __restrict__ parts, int N, int K, int kslice)
{
    const int z = blockIdx.z;
    float* out = parts + (size_t)z * kRows * N;
    gemm_body<0, 0, 0>(A, WT, nullptr, out, N, K,
                       blockIdx.y * 128, blockIdx.x * 128, z * kslice, (z + 1) * kslice);
}

__global__ __launch_bounds__(256)
void gemm_qkv_kernel(const ushort_t* __restrict__ A,
                     const ushort_t* wq, const ushort_t* wk, const ushort_t* wv,
                     const float* bq, const float* bk, const float* bv,
                     ushort_t* q, ushort_t* k, ushort_t* v)
{
    const ushort_t* WT; const float* bias; ushort_t* out;
    if (blockIdx.z == 0)      { WT = wq; bias = bq; out = q; }
    else if (blockIdx.z == 1) { WT = wk; bias = bk; out = k; }
    else                      { WT = wv; bias = bv; out = v; }
    gemm_body<0, 1, 1>(A, WT, bias, out, kD, kD,
                       blockIdx.y * 128, blockIdx.x * 128, 0, kD);
}

// ---------------------------------------------------------------------------
// Weight transpose + fp32->bf16:  W[K][N] -> WT[N][K] bf16.
// ---------------------------------------------------------------------------
struct WtDesc { const float* src; ushort_t* dst; int K; int N; };
struct WtArgs { WtDesc d[3]; };

__global__ __launch_bounds__(256)
void wt_kernel(WtArgs args)
{
    const WtDesc w = args.d[blockIdx.z];
    const int ktiles = w.K >> 6;
    const int kt = (blockIdx.x % ktiles) * 64;
    const int nt = (blockIdx.x / ktiles) * 64;
    if (nt >= w.N) return;

    __shared__ float T[64][65];
    const int tid = threadIdx.x;
    #pragma unroll
    for (int i = 0; i < 4; ++i) {
        const int e = tid + i * 256;
        const int r = e >> 4;
        const int c = (e & 15) * 4;
        const float4 f = *(const float4*)&w.src[(size_t)(kt + r) * w.N + nt + c];
        T[c + 0][r] = f.x; T[c + 1][r] = f.y; T[c + 2][r] = f.z; T[c + 3][r] = f.w;
    }
    __syncthreads();
    #pragma unroll
    for (int i = 0; i < 4; ++i) {
        const int e = tid + i * 256;
        const int n = e >> 4;
        const int kc = (e & 15) * 4;
        ushort4 o;
        o.x = f2bf(T[n][kc + 0]); o.y = f2bf(T[n][kc + 1]);
        o.z = f2bf(T[n][kc + 2]); o.w = f2bf(T[n][kc + 3]);
        *(ushort4*)&w.dst[(size_t)(nt + n) * w.K + kt + kc] = o;
    }
}

// fp32 -> bf16 elementwise
__global__ __launch_bounds__(256)
void cvt_kernel(const float* __restrict__ in, ushort_t* __restrict__ out, int n4)
{
    const int i = blockIdx.x * 256 + threadIdx.x;
    if (i < n4) {
        const float4 f = ((const float4*)in)[i];
        ushort4 o;
        o.x = f2bf(f.x); o.y = f2bf(f.y); o.z = f2bf(f.z); o.w = f2bf(f.w);
        ((ushort4*)out)[i] = o;
    }
}

// ---------------------------------------------------------------------------
// V transpose per head: vb[b*L+j][h*64+d] -> vt[(b*12+h)*64+d][j]
// ---------------------------------------------------------------------------
__global__ __launch_bounds__(256)
void vtrans_kernel(const ushort_t* __restrict__ vb, ushort_t* __restrict__ vt)
{
    const int bh = blockIdx.x;
    const int b = bh / kNH, h = bh - b * kNH;
    const int j0 = blockIdx.y * 64;
    __shared__ ushort_t T[64][72];

    const int tid = threadIdx.x;
    {
        const int jr = tid & 63;
        const int c0 = (tid >> 6) * 16;
        const ushort_t* sp = vb + (size_t)(b * kL + j0 + jr) * kD + h * kDK + c0;
        uint4 u0 = *(const uint4*)sp;
        uint4 u1 = *(const uint4*)(sp + 8);
        const ushort_t* e0 = (const ushort_t*)&u0;
        const ushort_t* e1 = (const ushort_t*)&u1;
        #pragma unroll
        for (int jj = 0; jj < 8; ++jj) {
            T[c0 + jj][jr]     = e0[jj];
            T[c0 + 8 + jj][jr] = e1[jj];
        }
    }
    __syncthreads();
    {
        const int dr = tid >> 2;
        const int jc = (tid & 3) * 16;
        ushort_t* dp = vt + (size_t)(bh * 64 + dr) * kL + j0 + jc;
        *(uint4*)dp       = *(const uint4*)&T[dr][jc];
        *(uint4*)(dp + 8) = *(const uint4*)&T[dr][jc + 8];
    }
}

// ---------------------------------------------------------------------------
// Relative-position bias table in MFMA-fragment order (see R5/R6 notes).
// ---------------------------------------------------------------------------
__global__ __launch_bounds__(256, 4)
void bias_kernel(const float* __restrict__ sx, const float* __restrict__ sy,
                 const float* __restrict__ P1, const float* __restrict__ pb1,
                 const float* __restrict__ P2, const float* __restrict__ pb2,
                 ushort_t* __restrict__ biasb)
{
    const int bid = blockIdx.x;
    const int b  = bid >> 10;
    const int qt = (bid >> 4) & 63;
    const int kt = bid & 15;
    const int tid = threadIdx.x;

    __shared__ float P[32][16];       // [u] = {A,B,C,0, W2[0..11]}
    __shared__ float pb2l[12];
    __shared__ float qxl[16], qyl[16], kxl[64], kyl[64];
    __shared__ ushort_t Btile[12 * 1024];   // 24 KB

    if (tid < 32) {
        P[tid][0] = P1[tid];
        P[tid][1] = P1[32 + tid];
        P[tid][2] = pb1[tid];
        P[tid][3] = 0.f;
    }
    for (int e = tid; e < 384; e += 256) P[e / 12][4 + e % 12] = P2[e];
    if (tid < 12) pb2l[tid] = pb2[tid];
    if (tid < 16) { qxl[tid] = sx[b * kL + qt * 16 + tid];
                    qyl[tid] = sy[b * kL + qt * 16 + tid]; }
    if (tid < 64) { kxl[tid] = sx[b * kL + kt * 64 + tid];
                    kyl[tid] = sy[b * kL + kt * 64 + tid]; }
    __syncthreads();

    const int ri = tid >> 4;
    const int fl = tid & 15;
    const int fq = ri >> 2, r = ri & 3;
    const int lane16 = fq * 16 + fl;
    const float xi = qxl[ri], yi = qyl[ri];

    float rx[4], ry[4];
    #pragma unroll
    for (int n = 0; n < 4; ++n) {
        const int cj = n * 16 + fl;
        rx[n] = fminf(fmaxf(xi - kxl[cj], -1000.f), 1000.f) * 1e-3f;
        ry[n] = fminf(fmaxf(yi - kyl[cj], -1000.f), 1000.f) * 1e-3f;
    }

    float acc[4][12] = {};
    #pragma unroll 4
    for (int u = 0; u < 32; ++u) {
        const float4 pc = *(const float4*)&P[u][0];
        const float4 w0 = *(const float4*)&P[u][4];
        const float4 w1 = *(const float4*)&P[u][8];
        const float4 w2 = *(const float4*)&P[u][12];
        float t[4];
        #pragma unroll
        for (int n = 0; n < 4; ++n)
            t[n] = fmaxf(fmaf(rx[n], pc.x, fmaf(ry[n], pc.y, pc.z)), 0.f);
        #pragma unroll
        for (int n = 0; n < 4; ++n) {
            acc[n][0]  = fmaf(t[n], w0.x, acc[n][0]);
            acc[n][1]  = fmaf(t[n], w0.y, acc[n][1]);
            acc[n][2]  = fmaf(t[n], w0.z, acc[n][2]);
            acc[n][3]  = fmaf(t[n], w0.w, acc[n][3]);
            acc[n][4]  = fmaf(t[n], w1.x, acc[n][4]);
            acc[n][5]  = fmaf(t[n], w1.y, acc[n][5]);
            acc[n][6]  = fmaf(t[n], w1.z, acc[n][6]);
            acc[n][7]  = fmaf(t[n], w1.w, acc[n][7]);
            acc[n][8]  = fmaf(t[n], w2.x, acc[n][8]);
            acc[n][9]  = fmaf(t[n], w2.y, acc[n][9]);
            acc[n][10] = fmaf(t[n], w2.z, acc[n][10]);
            acc[n][11] = fmaf(t[n], w2.w, acc[n][11]);
        }
    }

    #pragma unroll
    for (int h = 0; h < 12; ++h) {
        const float pb = pb2l[h];
        #pragma unroll
        for (int n = 0; n < 4; ++n)
            Btile[h * 1024 + lane16 * 16 + n * 4 + r] = f2bf(acc[n][h] + pb);
    }
    __syncthreads();

    #pragma unroll
    for (int i = 0; i < 6; ++i) {
        const int off = (i * 256 + tid) * 8;
        const int h = off >> 10;
        const int inner = off & 1023;
        ushort_t* dst = biasb +
            (((size_t)(b * kNH + h) * 64 + qt) * 16 + kt) * 1024 + inner;
        *(uint4*)dst = *(const uint4*)&Btile[off];
    }
}

// ---------------------------------------------------------------------------
// MFMA flash attention: one block = one (bh, qtile); 4 waves = 4 K-splits of
// 256 keys each.  LDS is WAVE-PRIVATE inside the K-loop -> NO barriers in the
// loop (within-wave LDS ordering is lgkmcnt, inserted by the compiler), so
// K/bias prefetch loads stay in flight across tiles (the old per-tile
// __syncthreads emitted s_waitcnt vmcnt(0) and killed the prefetch — R6-R10
// plateau).  One __syncthreads at the end, then in-LDS split combine and a
// single coalesced O write (no partial buffers, no combine kernel).
// ---------------------------------------------------------------------------
__global__ __launch_bounds__(256)
void attn_kernel(const ushort_t* __restrict__ qg, const ushort_t* __restrict__ kg,
                 const ushort_t* __restrict__ vt, const ushort_t* __restrict__ biasb,
                 ushort_t* __restrict__ og)
{
    const int bh = blockIdx.x;
    const int b  = bh / kNH, h = bh - b * kNH;
    const int qt = blockIdx.y;
    const int q0 = qt * 16;
    const int tid = threadIdx.x;
    const int z  = tid >> 6;          // wave = K-split
    const int lane = tid & 63;
    const int fl = lane & 15, fq = lane >> 4;

    __shared__ ushort_t Sp[4][16][72];   // per-wave P staging
    __shared__ ushort_t Ob[4][16][64];   // per-wave normalized O (bf16)
    __shared__ float2   Ml[4][16];       // per-wave (m, l) per q-row

    const size_t qoff = (size_t)(b * kL + q0 + fl) * kD + h * kDK + fq * 8;
    const bf16x8 aq0 = *(const bf16x8*)(qg + qoff);
    const bf16x8 aq1 = *(const bf16x8*)(qg + qoff + 32);

    const ushort_t* kbase = kg + (size_t)(b * kL) * kD + h * kDK + fq * 8;
    const ushort_t* vbase = vt + (size_t)(bh * 64) * kL + fq * 8;
    const ushort_t* btile = biasb +
        ((size_t)(bh * 64 + qt) * 16 + z * 4) * 1024 + lane * 16;

    f32x4 accO[4] = {};
    float m_run[4] = {-INFINITY, -INFINITY, -INFINITY, -INFINITY};
    float l_run[4] = {};

    bf16x8 kc[4][2];
    uint4 bc0, bc1;
    {
        const int k0 = z * 256;
        #pragma unroll
        for (int n = 0; n < 4; ++n) {
            const ushort_t* kr = kbase + (size_t)(k0 + n * 16 + fl) * kD;
            kc[n][0] = *(const bf16x8*)kr;
            kc[n][1] = *(const bf16x8*)(kr + 32);
        }
        bc0 = *(const uint4*)btile;
        bc1 = *(const uint4*)(btile + 8);
    }

    #pragma unroll
    for (int t = 0; t < 4; ++t) {
        const int k0 = z * 256 + t * 64;

        bf16x8 vv[4][2];
        #pragma unroll
        for (int n = 0; n < 4; ++n) {
            const ushort_t* vr = vbase + (size_t)(n * 16 + fl) * kL + k0;
            vv[n][0] = *(const bf16x8*)vr;
            vv[n][1] = *(const bf16x8*)(vr + 32);
        }

        f32x4 S[4] = {};
        #pragma unroll
        for (int n = 0; n < 4; ++n) {
            S[n] = __builtin_amdgcn_mfma_f32_16x16x32_bf16(aq0, kc[n][0], S[n], 0, 0, 0);
            S[n] = __builtin_amdgcn_mfma_f32_16x16x32_bf16(aq1, kc[n][1], S[n], 0, 0, 0);
        }

        bf16x8 kn[4][2];
        uint4 bn0, bn1;
        if (t < 3) {
            #pragma unroll
            for (int n = 0; n < 4; ++n) {
                const ushort_t* kr = kbase + (size_t)(k0 + 64 + n * 16 + fl) * kD;
                kn[n][0] = *(const bf16x8*)kr;
                kn[n][1] = *(const bf16x8*)(kr + 32);
            }
            bn0 = *(const uint4*)(btile + (t + 1) * 1024);
            bn1 = *(const uint4*)(btile + (t + 1) * 1024 + 8);
        }

        ushort_t bu[16];
        *(uint4*)&bu[0] = bc0;
        *(uint4*)&bu[8] = bc1;
        #pragma unroll
        for (int n = 0; n < 4; ++n)
            #pragma unroll
            for (int r = 0; r < 4; ++r)
                S[n][r] = fmaf(S[n][r], 0.125f, bf2f(bu[n * 4 + r]));

        #pragma unroll
        for (int r = 0; r < 4; ++r) {
            float mx = fmaxf(fmaxf(S[0][r], S[1][r]), fmaxf(S[2][r], S[3][r]));
            mx = fmaxf(mx, __shfl_xor(mx, 1, 16));
            mx = fmaxf(mx, __shfl_xor(mx, 2, 16));
            mx = fmaxf(mx, __shfl_xor(mx, 4, 16));
            mx = fmaxf(mx, __shfl_xor(mx, 8, 16));
            const float mnew  = fmaxf(m_run[r], mx);
            const float alpha = __expf(m_run[r] - mnew);
            float ls = 0.f;
            #pragma unroll
            for (int n = 0; n < 4; ++n) {
                const float e = __expf(S[n][r] - mnew);
                S[n][r] = e;
                ls += e;
            }
            ls += __shfl_xor(ls, 1, 16);
            ls += __shfl_xor(ls, 2, 16);
            ls += __shfl_xor(ls, 4, 16);
            ls += __shfl_xor(ls, 8, 16);
            l_run[r] = l_run[r] * alpha + ls;
            m_run[r] = mnew;
            #pragma unroll
            for (int n = 0; n < 4; ++n) accO[n][r] *= alpha;
        }

        // P -> wave-private LDS (C-layout -> A-layout); no barrier needed:
        // same-wave ds ordering is handled by lgkmcnt / in-order DS pipe.
        #pragma unroll
        for (int n = 0; n < 4; ++n)
            #pragma unroll
            for (int r = 0; r < 4; ++r)
                Sp[z][fq * 4 + r][n * 16 + fl] = f2bf(S[n][r]);

        const bf16x8 ap0 = *(const bf16x8*)&Sp[z][fl][fq * 8];
        const bf16x8 ap1 = *(const bf16x8*)&Sp[z][fl][32 + fq * 8];
        #pragma unroll
        for (int n = 0; n < 4; ++n) {
            accO[n] = __builtin_amdgcn_mfma_f32_16x16x32_bf16(ap0, vv[n][0], accO[n], 0, 0, 0);
            accO[n] = __builtin_amdgcn_mfma_f32_16x16x32_bf16(ap1, vv[n][1], accO[n], 0, 0, 0);
        }

        if (t < 3) {
            #pragma unroll
            for (int n = 0; n < 4; ++n) { kc[n][0] = kn[n][0]; kc[n][1] = kn[n][1]; }
            bc0 = bn0; bc1 = bn1;
        }
    }

    // stage normalized per-split O + (m,l) for the block-level combine
    float inv[4];
    #pragma unroll
    for (int r = 0; r < 4; ++r) inv[r] = 1.0f / l_run[r];
    #pragma unroll
    for (int n = 0; n < 4; ++n)
        #pragma unroll
        for (int r = 0; r < 4; ++r)
            Ob[z][fq * 4 + r][n * 16 + fl] = f2bf(accO[n][r] * inv[r]);
    if (fl == 0) {
        #pragma unroll
        for (int r = 0; r < 4; ++r)
            Ml[z][fq * 4 + r] = make_float2(m_run[r], l_run[r]);
    }
    __syncthreads();

    // combine: thread -> (row ri, dims d0..d0+3); w_z ∝ e^{m_z-M} l_z
    {
        const int ri = tid >> 4;
        const int d0 = (tid & 15) * 4;
        const float2 s0 = Ml[0][ri], s1 = Ml[1][ri], s2 = Ml[2][ri], s3 = Ml[3][ri];
        const float M = fmaxf(fmaxf(s0.x, s1.x), fmaxf(s2.x, s3.x));
        const float w0 = __expf(s0.x - M) * s0.y;
        const float w1 = __expf(s1.x - M) * s1.y;
        const float w2 = __expf(s2.x - M) * s2.y;
        const float w3 = __expf(s3.x - M) * s3.y;
        const float winv = 1.0f / (w0 + w1 + w2 + w3);
        const float c0 = w0 * winv, c1 = w1 * winv, c2 = w2 * winv, c3 = w3 * winv;

        ushort_t o[4];
        #pragma unroll
        for (int j = 0; j < 4; ++j)
            o[j] = f2bf(fmaf(c0, bf2f(Ob[0][ri][d0 + j]),
                        fmaf(c1, bf2f(Ob[1][ri][d0 + j]),
                        fmaf(c2, bf2f(Ob[2][ri][d0 + j]),
                             c3 * bf2f(Ob[3][ri][d0 + j])))));
        *(uint2*)&og[(size_t)(b * kL + q0 + ri) * kD + h * kDK + d0] = *(const uint2*)o;
    }
}

// ---------------------------------------------------------------------------
// Residual + split-K reduce + bias + LayerNorm.
// ---------------------------------------------------------------------------
template<int NPART, int DUAL>
__global__ __launch_bounds__(256)
void ln_kernel(const float* __restrict__ a, const float* __restrict__ parts,
               const float* __restrict__ bias,
               const float* __restrict__ g, const float* __restrict__ be,
               float* __restrict__ out, ushort_t* __restrict__ out_bf)
{
    const int row = blockIdx.x;
    const int tid = threadIdx.x;
    const float* pa = a + (size_t)row * kD;
    constexpr size_t NTOK = (size_t)kRows * kD;

    float v[3];
    float s = 0.f, sq = 0.f;
    #pragma unroll
    for (int i = 0; i < 3; ++i) {
        const int d = tid + i * 256;
        float t = pa[d] + bias[d];
        #pragma unroll
        for (int p = 0; p < NPART; ++p)
            t += parts[p * NTOK + (size_t)row * kD + d];
        v[i] = t;
        s  += t;
        sq += t * t;
    }
    #pragma unroll
    for (int off = 32; off > 0; off >>= 1) {
        s  += __shfl_down(s, off);
        sq += __shfl_down(sq, off);
    }
    __shared__ float bs[4], bq2[4];
    if ((tid & 63) == 0) { bs[tid >> 6] = s; bq2[tid >> 6] = sq; }
    __syncthreads();
    const float ts = bs[0] + bs[1] + bs[2] + bs[3];
    const float tq = bq2[0] + bq2[1] + bq2[2] + bq2[3];
    const float invn = 1.0f / (float)kD;
    const float mean = ts * invn;
    const float var  = tq * invn - mean * mean;
    const float rstd = rsqrtf(var + kEPS);

    float* po = out + (size_t)row * kD;
    #pragma unroll
    for (int i = 0; i < 3; ++i) {
        const int d = tid + i * 256;
        const float o = (v[i] - mean) * rstd * g[d] + be[d];
        po[d] = o;
        if (DUAL) out_bf[(size_t)row * kD + d] = f2bf(o);
    }
}

// ---------------------------------------------------------------------------
extern "C" void kernel_launch(void* const* d_in, const int* in_sizes, int n_in,
                              void* d_out, int out_size, void* d_ws, size_t ws_size,
                              hipStream_t stream)
{
    const float* src = (const float*)d_in[0];
    const float* sx  = (const float*)d_in[1];
    const float* sy  = (const float*)d_in[2];
    const float* Wq  = (const float*)d_in[3];  const float* bq  = (const float*)d_in[4];
    const float* Wk  = (const float*)d_in[5];  const float* bk  = (const float*)d_in[6];
    const float* Wv  = (const float*)d_in[7];  const float* bv  = (const float*)d_in[8];
    const float* Wo  = (const float*)d_in[9];  const float* bo  = (const float*)d_in[10];
    const float* P1  = (const float*)d_in[11]; const float* pb1 = (const float*)d_in[12];
    const float* P2  = (const float*)d_in[13]; const float* pb2 = (const float*)d_in[14];
    const float* W1  = (const float*)d_in[15]; const float* b1  = (const float*)d_in[16];
    const float* W2  = (const float*)d_in[17]; const float* b2  = (const float*)d_in[18];
    const float* g1  = (const float*)d_in[19]; const float* be1 = (const float*)d_in[20];
    const float* g2  = (const float*)d_in[21]; const float* be2 = (const float*)d_in[22];

    // ---- workspace arena (ushort units) ----
    constexpr size_t W768  = 768u * 768u;
    constexpr size_t W3072 = 768u * 3072u;
    constexpr size_t NTOK  = (size_t)kRows * kD;

    ushort_t* wsu = (ushort_t*)d_ws;
    ushort_t* wqT = wsu;
    ushort_t* wkT = wqT + W768;
    ushort_t* wvT = wkT + W768;
    ushort_t* qb  = wvT + W768;          // Q; dead after attn -> xbf
    ushort_t* kb  = qb + NTOK;
    ushort_t* vb  = kb + NTOK;
    ushort_t* sb  = vb + NTOK;           // src_bf -> attn out
    ushort_t* vtb = sb + NTOK;
    ushort_t* biasb = vtb + NTOK;        // 50 MB bias; reused after attn:
    ushort_t* woT   = biasb;
    ushort_t* w1T   = woT + W768;
    ushort_t* w2T   = w1T + W3072;
    float*    xb    = (float*)(w2T + W3072);
    ushort_t* h1bf  = (ushort_t*)(xb + NTOK);
    float*    s2p   = (float*)h1bf;
    float*    ff2p  = (float*)(h1bf + 4 * NTOK);
    ushort_t* xbf   = qb;

    const dim3 blk(256);

    WtArgs wa_early;
    wa_early.d[0] = { Wq, wqT, kD, kD };
    wa_early.d[1] = { Wk, wkT, kD, kD };
    wa_early.d[2] = { Wv, wvT, kD, kD };
    wt_kernel<<<dim3(144, 1, 3), blk, 0, stream>>>(wa_early);
    cvt_kernel<<<dim3((int)(NTOK / 4 / 256)), blk, 0, stream>>>(src, sb, (int)(NTOK / 4));
    bias_kernel<<<dim3(2048), blk, 0, stream>>>(sx, sy, P1, pb1, P2, pb2, biasb);

    gemm_qkv_kernel<<<dim3(kD / 128, kRows / 128, 3), blk, 0, stream>>>(
        sb, wqT, wkT, wvT, bq, bk, bv, qb, kb, vb);

    vtrans_kernel<<<dim3(2 * kNH, kL / 64), blk, 0, stream>>>(vb, vtb);

    // attention: 4 waves/block = 4 K-splits, in-block combine, O -> sb
    attn_kernel<<<dim3(2 * kNH, kL / 16), blk, 0, stream>>>(qb, kb, vtb, biasb, sb);

    WtArgs wa_late;
    wa_late.d[0] = { Wo, woT, kD,  kD  };
    wa_late.d[1] = { W1, w1T, kD,  kFF };
    wa_late.d[2] = { W2, w2T, kFF, kD  };
    wt_kernel<<<dim3(576, 1, 3), blk, 0, stream>>>(wa_late);

    gemm_splitk_kernel<<<dim3(kD / 128, kRows / 128, 2), blk, 0, stream>>>(
        sb, woT, s2p, kD, kD, kD / 2);

    ln_kernel<2, 1><<<dim3(kRows), blk, 0, stream>>>(src, s2p, bo, g1, be1, xb, xbf);

    gemm_kernel<1, 1><<<dim3(kFF / 128, kRows / 128), blk, 0, stream>>>(
        xbf, w1T, b1, h1bf, kFF, kD);

    gemm_splitk_kernel<<<dim3(kD / 128, kRows / 128, 3), blk, 0, stream>>>(
        h1bf, w2T, ff2p, kD, kFF, kFF / 3);

    ln_kernel<3, 0><<<dim3(kRows), blk, 0, stream>>>(xb, ff2p, b2, g2, be2,
                                                     (float*)d_out, nullptr);
}